// Round 2
// baseline (9232.713 us; speedup 1.0000x reference)
//
#include <hip/hip_runtime.h>
#include <hip/hip_bf16.h>
#include <math.h>

using bf16 = __hip_bfloat16;

constexpr int Bc = 4, Sc = 4096, Dc = 1024, Hc = 16, DHc = 64, Fc = 64, DFFc = 4096;
constexpr float EPS_LN_C = 1e-5f, EPS_ATTN_C = 1e-6f;

static __device__ __forceinline__ float bf2f(unsigned short u) {
  union { unsigned int i; float f; } x; x.i = ((unsigned)u) << 16; return x.f;
}
static __device__ __forceinline__ float b2f(bf16 v) { return __bfloat162float(v); }
static __device__ __forceinline__ bf16 f2b(float f) { return __float2bfloat16(f); }

// ---------------- block reduction (256 threads, wave64) ----------------
__device__ float block_reduce_sum(float v) {
  __shared__ float red[4];
  int lane = threadIdx.x & 63, wid = threadIdx.x >> 6;
#pragma unroll
  for (int off = 32; off > 0; off >>= 1) v += __shfl_down(v, off, 64);
  __syncthreads();              // protect red[] from previous use
  if (lane == 0) red[wid] = v;
  __syncthreads();
  return red[0] + red[1] + red[2] + red[3];
}

// ---------------- LayerNorm: one block per row (D=1024) ----------------
__global__ void ln_kernel(const float* __restrict__ x, const float* __restrict__ g,
                          const float* __restrict__ bta, bf16* __restrict__ out) {
  int row = blockIdx.x;
  const float* xr = x + (size_t)row * Dc;
  int t = threadIdx.x;
  float v[4];
#pragma unroll
  for (int i = 0; i < 4; ++i) v[i] = xr[t + 256 * i];
  float s = block_reduce_sum(v[0] + v[1] + v[2] + v[3]);
  float mu = s * (1.f / Dc);
  float vs = 0.f;
#pragma unroll
  for (int i = 0; i < 4; ++i) { float d = v[i] - mu; vs += d * d; }
  vs = block_reduce_sum(vs);
  float rstd = rsqrtf(vs * (1.f / Dc) + EPS_LN_C);
  bf16* orow = out + (size_t)row * Dc;
#pragma unroll
  for (int i = 0; i < 4; ++i) {
    int c = t + 256 * i;
    orow[c] = f2b((v[i] - mu) * rstd * g[c] + bta[c]);
  }
}

// ---------------- Generic tiled GEMM: C = A(bf16)[M,K] * B(f32)[K,N], B row-stride ldb ----
// EPI: 0 -> outB = AB                      (bf16 store)
//      1 -> outF = AB + bias + res        (f32 store)
//      2 -> outB = gelu(AB + bias)        (bf16 store)
//      3 -> outF = AB + (bias?) + res (res==outF ok, in-place f32)
template <int EPI>
__global__ void gemm_kernel(const bf16* __restrict__ A, const float* __restrict__ Bw,
                            const float* __restrict__ bias, const float* __restrict__ res,
                            float* __restrict__ outF, bf16* __restrict__ outB,
                            int M, int N, int K, int ldb) {
  __shared__ float As[16][65];   // [k][m]
  __shared__ float Bs[16][65];   // [k][n]
  int tid = threadIdx.x;
  int row0 = blockIdx.y * 64, col0 = blockIdx.x * 64;
  int tx = tid & 15, ty = tid >> 4;
  int a_r = tid >> 2, a_k = (tid & 3) << 2;
  int b_k = tid >> 4, b_n = (tid & 15) << 2;
  float acc[4][4] = {};
  for (int k0 = 0; k0 < K; k0 += 16) {
    ushort4 av = *(const ushort4*)(A + (size_t)(row0 + a_r) * K + k0 + a_k);
    As[a_k + 0][a_r] = bf2f(av.x);
    As[a_k + 1][a_r] = bf2f(av.y);
    As[a_k + 2][a_r] = bf2f(av.z);
    As[a_k + 3][a_r] = bf2f(av.w);
    float4 bv = *(const float4*)(Bw + (size_t)(k0 + b_k) * ldb + col0 + b_n);
    Bs[b_k][b_n + 0] = bv.x; Bs[b_k][b_n + 1] = bv.y;
    Bs[b_k][b_n + 2] = bv.z; Bs[b_k][b_n + 3] = bv.w;
    __syncthreads();
#pragma unroll
    for (int kk = 0; kk < 16; ++kk) {
      float ar[4], br[4];
#pragma unroll
      for (int i = 0; i < 4; ++i) ar[i] = As[kk][ty * 4 + i];
#pragma unroll
      for (int j = 0; j < 4; ++j) br[j] = Bs[kk][tx * 4 + j];
#pragma unroll
      for (int i = 0; i < 4; ++i)
#pragma unroll
        for (int j = 0; j < 4; ++j) acc[i][j] = fmaf(ar[i], br[j], acc[i][j]);
    }
    __syncthreads();
  }
#pragma unroll
  for (int i = 0; i < 4; ++i) {
    int r = row0 + ty * 4 + i;
#pragma unroll
    for (int j = 0; j < 4; ++j) {
      int c = col0 + tx * 4 + j;
      float v = acc[i][j];
      if (EPI == 1 || EPI == 2) v += bias[c];
      if (EPI == 3) { if (bias) v += bias[c]; }
      if (EPI == 2) v = 0.5f * v * (1.f + erff(v * 0.70710678118654752f));
      if (EPI == 1 || EPI == 3) v += res[(size_t)r * N + c];
      if (EPI == 0 || EPI == 2) outB[(size_t)r * N + c] = f2b(v);
      else outF[(size_t)r * N + c] = v;
    }
  }
}

// ---------------- feature map: per head, [S,DH] @ proj[DH,F], relu + eps ----------------
// grid (S/64, H, B); in: [B*S, H*DH] bf16; out: [B,H,S,F] bf16
__global__ void fm_kernel(const bf16* __restrict__ qin, const float* __restrict__ proj,
                          bf16* __restrict__ qf) {
  __shared__ float pj[64][65];  // [d][f]
  __shared__ float qs[64][65];  // [s_local][d]
  int t = threadIdx.x;
  int b = blockIdx.z, h = blockIdx.y, s0 = blockIdx.x * 64;
#pragma unroll
  for (int i = 0; i < 16; ++i) {
    int idx = t + 256 * i;
    pj[idx >> 6][idx & 63] = proj[idx];
    int sl = idx >> 6, d = idx & 63;
    qs[sl][d] = b2f(qin[((size_t)(b * Sc + s0 + sl)) * (Hc * DHc) + h * DHc + d]);
  }
  __syncthreads();
  size_t obase = (((size_t)(b * Hc + h)) * Sc + s0) * Fc;
#pragma unroll
  for (int i = 0; i < 16; ++i) {
    int idx = t + 256 * i;
    int sl = idx >> 6, f = idx & 63;
    float acc = 0.f;
#pragma unroll 8
    for (int d = 0; d < 64; ++d) acc += qs[sl][d] * pj[d][f];
    acc = fmaxf(acc, 0.f) + EPS_ATTN_C;
    qf[obase + (size_t)sl * Fc + f] = f2b(acc);
  }
}

// ---------------- kv = kf^T v, ksum = sum_s kf : one block per (b,h) ----------------
__global__ void kv_kernel(const bf16* __restrict__ kf, const bf16* __restrict__ v,
                          float* __restrict__ kv, float* __restrict__ ksum) {
  int bh = blockIdx.x;
  int b = bh >> 4, h = bh & 15;
  __shared__ float ks[64][65];  // [s_local][f]
  __shared__ float vs[64][65];  // [s_local][d]
  int t = threadIdx.x;
  int f = t & 63, dg = t >> 6;
  float acc[16] = {};
  float sacc = 0.f;
  for (int s0 = 0; s0 < Sc; s0 += 64) {
#pragma unroll
    for (int i = 0; i < 16; ++i) {
      int idx = t + 256 * i;
      int sl = idx >> 6, c = idx & 63;
      ks[sl][c] = b2f(kf[(((size_t)bh * Sc) + s0 + sl) * Fc + c]);
      vs[sl][c] = b2f(v[((size_t)(b * Sc + s0 + sl)) * (Hc * DHc) + h * DHc + c]);
    }
    __syncthreads();
#pragma unroll 4
    for (int sl = 0; sl < 64; ++sl) {
      float kval = ks[sl][f];
      if (dg == 0) sacc += kval;
#pragma unroll
      for (int j = 0; j < 16; ++j) acc[j] += kval * vs[sl][dg * 16 + j];
    }
    __syncthreads();
  }
#pragma unroll
  for (int j = 0; j < 16; ++j) kv[((size_t)bh * 64 + f) * 64 + dg * 16 + j] = acc[j];
  if (dg == 0) ksum[bh * 64 + f] = sacc;
}

// ---------------- attn = (qf @ kv) / (qf . ksum + eps) ----------------
// grid (S/64, H, B); out: [B*S, H*DH] bf16
__global__ void attn_kernel(const bf16* __restrict__ qf, const float* __restrict__ kv,
                            const float* __restrict__ ksum, bf16* __restrict__ attn) {
  int b = blockIdx.z, h = blockIdx.y, s0 = blockIdx.x * 64;
  int bh = b * Hc + h;
  __shared__ float kvs[64][65];  // [f][d]
  __shared__ float qs[64][65];   // [s_local][f]
  __shared__ float kss[64];
  int t = threadIdx.x;
#pragma unroll
  for (int i = 0; i < 16; ++i) {
    int idx = t + 256 * i;
    kvs[idx >> 6][idx & 63] = kv[(size_t)bh * 4096 + idx];
    int sl = idx >> 6, f = idx & 63;
    qs[sl][f] = b2f(qf[(((size_t)bh * Sc) + s0 + sl) * Fc + f]);
  }
  if (t < 64) kss[t] = ksum[bh * 64 + t];
  __syncthreads();
  int sl = t & 63, dg = t >> 6;
  float den = EPS_ATTN_C;
#pragma unroll 8
  for (int f = 0; f < 64; ++f) den += qs[sl][f] * kss[f];
  float inv = 1.0f / den;
  size_t orow = ((size_t)(b * Sc + s0 + sl)) * (Hc * DHc) + h * DHc;
#pragma unroll
  for (int j = 0; j < 16; ++j) {
    int d = dg * 16 + j;
    float acc = 0.f;
#pragma unroll 8
    for (int f = 0; f < 64; ++f) acc += qs[sl][f] * kvs[f][d];
    attn[orow + d] = f2b(acc * inv);
  }
}

extern "C" void kernel_launch(void* const* d_in, const int* in_sizes, int n_in,
                              void* d_out, int out_size, void* d_ws, size_t ws_size,
                              hipStream_t stream) {
  const float* x     = (const float*)d_in[0];
  const float* ln1_g = (const float*)d_in[1];
  const float* ln1_b = (const float*)d_in[2];
  const float* wq    = (const float*)d_in[3];
  const float* wk    = (const float*)d_in[4];
  const float* wv    = (const float*)d_in[5];
  const float* proj  = (const float*)d_in[6];
  const float* wo    = (const float*)d_in[7];
  const float* bo    = (const float*)d_in[8];
  const float* ln2_g = (const float*)d_in[9];
  const float* ln2_b = (const float*)d_in[10];
  const float* w1    = (const float*)d_in[11];
  const float* b1    = (const float*)d_in[12];
  const float* w2    = (const float*)d_in[13];
  const float* b2    = (const float*)d_in[14];
  float* out = (float*)d_out;
  (void)ws_size; (void)in_sizes; (void)n_in; (void)out_size;

  // ---- workspace plan (peak ~129.1 MB) ----
  // R0..R3: 32 MB bf16 regions (TOK x 1024). mid (64 MB, TOK x 2048 bf16) aliases R1+R2.
  const size_t TOK = (size_t)Bc * Sc;           // 16384
  const size_t REG = TOK * Dc * sizeof(bf16);   // 32 MB
  char* ws = (char*)d_ws;
  bf16* R0 = (bf16*)(ws + 0 * REG);             // h -> qf -> h2
  bf16* R1 = (bf16*)(ws + 1 * REG);             // q -> kf -> mid(lo half)
  bf16* R2 = (bf16*)(ws + 2 * REG);             // k -> attn -> mid(hi half)
  bf16* R3 = (bf16*)(ws + 3 * REG);             // v
  bf16* mid = R1;                               // TOK x 2048 bf16 spans R1+R2
  float* kvb = (float*)(ws + 4 * REG);                          // 1 MB
  float* ksb = (float*)(ws + 4 * REG + (size_t)Bc * Hc * Fc * DHc * 4);  // 16 KB

  dim3 blk(256);
  // 1. h = LN1(x) -> R0
  ln_kernel<<<dim3(TOK), blk, 0, stream>>>(x, ln1_g, ln1_b, R0);
  // 2-4. q,k,v = h @ {wq,wk,wv}
  dim3 gD(Dc / 64, TOK / 64);
  gemm_kernel<0><<<gD, blk, 0, stream>>>(R0, wq, nullptr, nullptr, nullptr, R1, TOK, Dc, Dc, Dc);
  gemm_kernel<0><<<gD, blk, 0, stream>>>(R0, wk, nullptr, nullptr, nullptr, R2, TOK, Dc, Dc, Dc);
  gemm_kernel<0><<<gD, blk, 0, stream>>>(R0, wv, nullptr, nullptr, nullptr, R3, TOK, Dc, Dc, Dc);
  // 5-6. qf = fm(q): R1 -> R0 (h dead); kf = fm(k): R2 -> R1 (q dead)
  dim3 gF(Sc / 64, Hc, Bc);
  fm_kernel<<<gF, blk, 0, stream>>>(R1, proj, R0);
  fm_kernel<<<gF, blk, 0, stream>>>(R2, proj, R1);
  // 7. kv, ksum from kf(R1), v(R3)
  kv_kernel<<<dim3(Bc * Hc), blk, 0, stream>>>(R1, R3, kvb, ksb);
  // 8. attn from qf(R0) -> R2 (k dead)
  attn_kernel<<<gF, blk, 0, stream>>>(R0, kvb, ksb, R2);
  // 9. x2 = x + attn @ wo + bo  -> d_out (f32)
  gemm_kernel<1><<<gD, blk, 0, stream>>>(R2, wo, bo, x, out, nullptr, TOK, Dc, Dc, Dc);
  // 10. h2 = LN2(x2) -> R0 (qf dead)
  ln_kernel<<<dim3(TOK), blk, 0, stream>>>(out, ln2_g, ln2_b, R0);
  // 11-12. FFN split over DFF into two 2048-column halves (mid aliases R1+R2; attn dead)
  dim3 gW1(2048 / 64, TOK / 64);
  // half 0: mid = gelu(h2 @ w1[:, :2048] + b1[:2048]);  out += mid @ w2[:2048,:] + b2
  gemm_kernel<2><<<gW1, blk, 0, stream>>>(R0, w1, b1, nullptr, nullptr, mid, TOK, 2048, Dc, DFFc);
  gemm_kernel<3><<<gD, blk, 0, stream>>>(mid, w2, b2, out, out, nullptr, TOK, Dc, 2048, Dc);
  // half 1: mid = gelu(h2 @ w1[:, 2048:] + b1[2048:]);  out += mid @ w2[2048:,:]  (no bias)
  gemm_kernel<2><<<gW1, blk, 0, stream>>>(R0, w1 + 2048, b1 + 2048, nullptr, nullptr, mid, TOK, 2048, Dc, DFFc);
  gemm_kernel<3><<<gD, blk, 0, stream>>>(mid, w2 + (size_t)2048 * Dc, nullptr, out, out, nullptr, TOK, Dc, 2048, Dc);
}

// Round 3
// 2388.816 us; speedup vs baseline: 3.8650x; 3.8650x over previous
//
#include <hip/hip_runtime.h>
#include <hip/hip_bf16.h>
#include <math.h>

using bf16 = __hip_bfloat16;
typedef __attribute__((ext_vector_type(8))) short short8;
typedef __attribute__((ext_vector_type(4))) float f32x4;

constexpr int Bc = 4, Sc = 4096, Dc = 1024, Hc = 16, DHc = 64, Fc = 64, DFFc = 4096;
constexpr float EPS_LN_C = 1e-5f, EPS_ATTN_C = 1e-6f;

static __device__ __forceinline__ float b2f(bf16 v) { return __bfloat162float(v); }
static __device__ __forceinline__ bf16 f2b(float f) { return __float2bfloat16(f); }

// ---------------- block reduction (256 threads, wave64) ----------------
__device__ float block_reduce_sum(float v) {
  __shared__ float red[4];
  int lane = threadIdx.x & 63, wid = threadIdx.x >> 6;
#pragma unroll
  for (int off = 32; off > 0; off >>= 1) v += __shfl_down(v, off, 64);
  __syncthreads();
  if (lane == 0) red[wid] = v;
  __syncthreads();
  return red[0] + red[1] + red[2] + red[3];
}

// ---------------- LayerNorm: one block per row (D=1024) ----------------
__global__ void ln_kernel(const float* __restrict__ x, const float* __restrict__ g,
                          const float* __restrict__ bta, bf16* __restrict__ out) {
  int row = blockIdx.x;
  const float* xr = x + (size_t)row * Dc;
  int t = threadIdx.x;
  float v[4];
#pragma unroll
  for (int i = 0; i < 4; ++i) v[i] = xr[t + 256 * i];
  float s = block_reduce_sum(v[0] + v[1] + v[2] + v[3]);
  float mu = s * (1.f / Dc);
  float vs = 0.f;
#pragma unroll
  for (int i = 0; i < 4; ++i) { float d = v[i] - mu; vs += d * d; }
  vs = block_reduce_sum(vs);
  float rstd = rsqrtf(vs * (1.f / Dc) + EPS_LN_C);
  bf16* orow = out + (size_t)row * Dc;
#pragma unroll
  for (int i = 0; i < 4; ++i) {
    int c = t + 256 * i;
    orow[c] = f2b((v[i] - mu) * rstd * g[c] + bta[c]);
  }
}

// ------------- transpose + convert: in f32 [K,N] -> out bf16 [N,K] -------------
__global__ void tcvt_kernel(const float* __restrict__ in, bf16* __restrict__ out,
                            int K, int N) {
  __shared__ float t[32][33];
  int n0 = blockIdx.x * 32, k0 = blockIdx.y * 32;
  int tid = threadIdx.x;
#pragma unroll
  for (int i = 0; i < 4; ++i) {
    int idx = tid + 256 * i;
    int r = idx >> 5, c = idx & 31;
    t[r][c] = in[(size_t)(k0 + r) * N + n0 + c];
  }
  __syncthreads();
#pragma unroll
  for (int i = 0; i < 4; ++i) {
    int idx = tid + 256 * i;
    int r = idx >> 5, c = idx & 31;
    out[(size_t)(n0 + r) * K + k0 + c] = f2b(t[c][r]);
  }
}

// ---------------- MFMA GEMM: C[M,N] = A(bf16)[M,lda] * Bt(bf16)[N,ldbt]^T ----------------
// 128x128 tile, BK=32, 4 waves each 64x64 (4x4 mfma_f32_16x16x32_bf16).
// EPI: 0 -> outB = AB (bf16)
//      1 -> outF = AB + bias + res (f32)
//      2 -> outB = gelu(AB + bias) (bf16)
//      3 -> outF = AB + (bias?) + res (res==outF ok, f32)
template <int EPI>
__global__ __launch_bounds__(256, 2)
void mgemm_kernel(const ushort* __restrict__ A, const ushort* __restrict__ Bt,
                  const float* __restrict__ bias, const float* __restrict__ res,
                  float* __restrict__ outF, bf16* __restrict__ outB,
                  int M, int N, int K, int lda, int ldbt) {
  __shared__ ushort As[128 * 32];
  __shared__ ushort Bs[128 * 32];
  int tid = threadIdx.x;
  int wave = tid >> 6, lane = tid & 63;
  int row0 = blockIdx.y * 128, col0 = blockIdx.x * 128;
  int wm = (wave >> 1) * 64, wn = (wave & 1) * 64;
  int mrow = lane & 15, quad = lane >> 4;

  f32x4 acc[4][4] = {};

  // staging chunk ids: chunk c covers tile row c>>2, elems (c&3)*8 .. +8 (16 B)
  int c0 = tid, c1 = tid + 256;
  const ushort* aP0 = A + (size_t)(row0 + (c0 >> 2)) * lda + (c0 & 3) * 8;
  const ushort* aP1 = A + (size_t)(row0 + (c1 >> 2)) * lda + (c1 & 3) * 8;
  const ushort* bP0 = Bt + (size_t)(col0 + (c0 >> 2)) * ldbt + (c0 & 3) * 8;
  const ushort* bP1 = Bt + (size_t)(col0 + (c1 >> 2)) * ldbt + (c1 & 3) * 8;
  ushort* aL0 = As + c0 * 8;
  ushort* aL1 = As + c1 * 8;
  ushort* bL0 = Bs + c0 * 8;
  ushort* bL1 = Bs + c1 * 8;

  for (int k0 = 0; k0 < K; k0 += 32) {
    __syncthreads();  // LDS reads of previous iter done before overwrite
    __builtin_amdgcn_global_load_lds((const __attribute__((address_space(1))) void*)aP0,
                                     (__attribute__((address_space(3))) void*)aL0, 16, 0, 0);
    __builtin_amdgcn_global_load_lds((const __attribute__((address_space(1))) void*)aP1,
                                     (__attribute__((address_space(3))) void*)aL1, 16, 0, 0);
    __builtin_amdgcn_global_load_lds((const __attribute__((address_space(1))) void*)bP0,
                                     (__attribute__((address_space(3))) void*)bL0, 16, 0, 0);
    __builtin_amdgcn_global_load_lds((const __attribute__((address_space(1))) void*)bP1,
                                     (__attribute__((address_space(3))) void*)bL1, 16, 0, 0);
    aP0 += 32; aP1 += 32; bP0 += 32; bP1 += 32;
    __syncthreads();  // staging complete

    short8 af[4], bfv[4];
#pragma unroll
    for (int i = 0; i < 4; ++i)
      af[i] = *(const short8*)(As + (wm + i * 16 + mrow) * 32 + quad * 8);
#pragma unroll
    for (int j = 0; j < 4; ++j)
      bfv[j] = *(const short8*)(Bs + (wn + j * 16 + mrow) * 32 + quad * 8);
#pragma unroll
    for (int i = 0; i < 4; ++i)
#pragma unroll
      for (int j = 0; j < 4; ++j)
        acc[i][j] = __builtin_amdgcn_mfma_f32_16x16x32_bf16(af[i], bfv[j], acc[i][j], 0, 0, 0);
  }

  // epilogue: D row = quad*4 + r, col = mrow (within 16x16 tile)
#pragma unroll
  for (int i = 0; i < 4; ++i) {
#pragma unroll
    for (int j = 0; j < 4; ++j) {
      int rb = row0 + wm + i * 16 + quad * 4;
      int c = col0 + wn + j * 16 + mrow;
#pragma unroll
      for (int r = 0; r < 4; ++r) {
        int rr = rb + r;
        float v = acc[i][j][r];
        if (EPI == 1 || EPI == 2) v += bias[c];
        if (EPI == 3) { if (bias) v += bias[c]; }
        if (EPI == 2) v = 0.5f * v * (1.f + erff(v * 0.70710678118654752f));
        if (EPI == 1 || EPI == 3) v += res[(size_t)rr * N + c];
        if (EPI == 0 || EPI == 2) outB[(size_t)rr * N + c] = f2b(v);
        else outF[(size_t)rr * N + c] = v;
      }
    }
  }
}

// ---------------- feature map: per head, [S,DH] @ proj[DH,F], relu + eps ----------------
__global__ void fm_kernel(const bf16* __restrict__ qin, const float* __restrict__ proj,
                          bf16* __restrict__ qf) {
  __shared__ float pj[64][65];
  __shared__ float qs[64][65];
  int t = threadIdx.x;
  int b = blockIdx.z, h = blockIdx.y, s0 = blockIdx.x * 64;
#pragma unroll
  for (int i = 0; i < 16; ++i) {
    int idx = t + 256 * i;
    pj[idx >> 6][idx & 63] = proj[idx];
    int sl = idx >> 6, d = idx & 63;
    qs[sl][d] = b2f(qin[((size_t)(b * Sc + s0 + sl)) * (Hc * DHc) + h * DHc + d]);
  }
  __syncthreads();
  size_t obase = (((size_t)(b * Hc + h)) * Sc + s0) * Fc;
#pragma unroll
  for (int i = 0; i < 16; ++i) {
    int idx = t + 256 * i;
    int sl = idx >> 6, f = idx & 63;
    float acc = 0.f;
#pragma unroll 8
    for (int d = 0; d < 64; ++d) acc += qs[sl][d] * pj[d][f];
    acc = fmaxf(acc, 0.f) + EPS_ATTN_C;
    qf[obase + (size_t)sl * Fc + f] = f2b(acc);
  }
}

// ---------------- kv = kf^T v, ksum = sum_s kf : one block per (b,h) ----------------
__global__ void kv_kernel(const bf16* __restrict__ kf, const bf16* __restrict__ v,
                          float* __restrict__ kv, float* __restrict__ ksum) {
  int bh = blockIdx.x;
  int b = bh >> 4, h = bh & 15;
  __shared__ float ks[64][65];
  __shared__ float vs[64][65];
  int t = threadIdx.x;
  int f = t & 63, dg = t >> 6;
  float acc[16] = {};
  float sacc = 0.f;
  for (int s0 = 0; s0 < Sc; s0 += 64) {
#pragma unroll
    for (int i = 0; i < 16; ++i) {
      int idx = t + 256 * i;
      int sl = idx >> 6, c = idx & 63;
      ks[sl][c] = b2f(kf[(((size_t)bh * Sc) + s0 + sl) * Fc + c]);
      vs[sl][c] = b2f(v[((size_t)(b * Sc + s0 + sl)) * (Hc * DHc) + h * DHc + c]);
    }
    __syncthreads();
#pragma unroll 4
    for (int sl = 0; sl < 64; ++sl) {
      float kval = ks[sl][f];
      if (dg == 0) sacc += kval;
#pragma unroll
      for (int j = 0; j < 16; ++j) acc[j] += kval * vs[sl][dg * 16 + j];
    }
    __syncthreads();
  }
#pragma unroll
  for (int j = 0; j < 16; ++j) kv[((size_t)bh * 64 + f) * 64 + dg * 16 + j] = acc[j];
  if (dg == 0) ksum[bh * 64 + f] = sacc;
}

// ---------------- attn = (qf @ kv) / (qf . ksum + eps) ----------------
__global__ void attn_kernel(const bf16* __restrict__ qf, const float* __restrict__ kv,
                            const float* __restrict__ ksum, bf16* __restrict__ attn) {
  int b = blockIdx.z, h = blockIdx.y, s0 = blockIdx.x * 64;
  int bh = b * Hc + h;
  __shared__ float kvs[64][65];
  __shared__ float qs[64][65];
  __shared__ float kss[64];
  int t = threadIdx.x;
#pragma unroll
  for (int i = 0; i < 16; ++i) {
    int idx = t + 256 * i;
    kvs[idx >> 6][idx & 63] = kv[(size_t)bh * 4096 + idx];
    int sl = idx >> 6, f = idx & 63;
    qs[sl][f] = b2f(qf[(((size_t)bh * Sc) + s0 + sl) * Fc + f]);
  }
  if (t < 64) kss[t] = ksum[bh * 64 + t];
  __syncthreads();
  int sl = t & 63, dg = t >> 6;
  float den = EPS_ATTN_C;
#pragma unroll 8
  for (int f = 0; f < 64; ++f) den += qs[sl][f] * kss[f];
  float inv = 1.0f / den;
  size_t orow = ((size_t)(b * Sc + s0 + sl)) * (Hc * DHc) + h * DHc;
#pragma unroll
  for (int j = 0; j < 16; ++j) {
    int d = dg * 16 + j;
    float acc = 0.f;
#pragma unroll 8
    for (int f = 0; f < 64; ++f) acc += qs[sl][f] * kvs[f][d];
    attn[orow + d] = f2b(acc * inv);
  }
}

extern "C" void kernel_launch(void* const* d_in, const int* in_sizes, int n_in,
                              void* d_out, int out_size, void* d_ws, size_t ws_size,
                              hipStream_t stream) {
  const float* x     = (const float*)d_in[0];
  const float* ln1_g = (const float*)d_in[1];
  const float* ln1_b = (const float*)d_in[2];
  const float* wq    = (const float*)d_in[3];
  const float* wk    = (const float*)d_in[4];
  const float* wv    = (const float*)d_in[5];
  const float* proj  = (const float*)d_in[6];
  const float* wo    = (const float*)d_in[7];
  const float* bo    = (const float*)d_in[8];
  const float* ln2_g = (const float*)d_in[9];
  const float* ln2_b = (const float*)d_in[10];
  const float* w1    = (const float*)d_in[11];
  const float* b1    = (const float*)d_in[12];
  const float* w2    = (const float*)d_in[13];
  const float* b2    = (const float*)d_in[14];
  float* out = (float*)d_out;
  (void)ws_size; (void)in_sizes; (void)n_in; (void)out_size;

  // ---- workspace plan (peak ~153 MB) ----
  const size_t TOK = (size_t)Bc * Sc;           // 16384
  const size_t REG = TOK * Dc * sizeof(bf16);   // 32 MB
  char* ws = (char*)d_ws;
  bf16* R0 = (bf16*)(ws + 0 * REG);             // h -> qf -> h2
  bf16* R1 = (bf16*)(ws + 1 * REG);             // q -> kf -> mid(lo)
  bf16* R2 = (bf16*)(ws + 2 * REG);             // k -> attn -> mid(hi)
  bf16* R3 = (bf16*)(ws + 3 * REG);             // v
  bf16* mid = R1;                               // TOK x 2048 bf16 spans R1+R2
  char* p = ws + 4 * REG;
  float* kvb = (float*)p;                 p += (size_t)Bc * Hc * Fc * DHc * 4;   // 1 MB
  float* ksb = (float*)p;                 p += (size_t)Bc * Hc * Fc * 4;         // 16 KB
  bf16* wqt = (bf16*)p;                   p += (size_t)Dc * Dc * 2;              // 2 MB
  bf16* wkt = (bf16*)p;                   p += (size_t)Dc * Dc * 2;
  bf16* wvt = (bf16*)p;                   p += (size_t)Dc * Dc * 2;
  bf16* wot = (bf16*)p;                   p += (size_t)Dc * Dc * 2;
  bf16* w1t = (bf16*)p;                   p += (size_t)Dc * DFFc * 2;            // 8 MB
  bf16* w2t = (bf16*)p;                   p += (size_t)Dc * DFFc * 2;            // 8 MB

  dim3 blk(256);
  // 0. transpose+convert weights to bf16 B^T form
  tcvt_kernel<<<dim3(Dc / 32, Dc / 32), blk, 0, stream>>>(wq, wqt, Dc, Dc);
  tcvt_kernel<<<dim3(Dc / 32, Dc / 32), blk, 0, stream>>>(wk, wkt, Dc, Dc);
  tcvt_kernel<<<dim3(Dc / 32, Dc / 32), blk, 0, stream>>>(wv, wvt, Dc, Dc);
  tcvt_kernel<<<dim3(Dc / 32, Dc / 32), blk, 0, stream>>>(wo, wot, Dc, Dc);
  tcvt_kernel<<<dim3(DFFc / 32, Dc / 32), blk, 0, stream>>>(w1, w1t, Dc, DFFc);
  tcvt_kernel<<<dim3(Dc / 32, DFFc / 32), blk, 0, stream>>>(w2, w2t, DFFc, Dc);

  // 1. h = LN1(x) -> R0
  ln_kernel<<<dim3(TOK), blk, 0, stream>>>(x, ln1_g, ln1_b, R0);

  // 2-4. q,k,v = h @ {wq,wk,wv}  (MFMA)
  dim3 gD(Dc / 128, TOK / 128);
  mgemm_kernel<0><<<gD, blk, 0, stream>>>((const ushort*)R0, (const ushort*)wqt, nullptr, nullptr,
                                          nullptr, R1, TOK, Dc, Dc, Dc, Dc);
  mgemm_kernel<0><<<gD, blk, 0, stream>>>((const ushort*)R0, (const ushort*)wkt, nullptr, nullptr,
                                          nullptr, R2, TOK, Dc, Dc, Dc, Dc);
  mgemm_kernel<0><<<gD, blk, 0, stream>>>((const ushort*)R0, (const ushort*)wvt, nullptr, nullptr,
                                          nullptr, R3, TOK, Dc, Dc, Dc, Dc);

  // 5-6. qf = fm(q): R1 -> R0 ; kf = fm(k): R2 -> R1
  dim3 gF(Sc / 64, Hc, Bc);
  fm_kernel<<<gF, blk, 0, stream>>>(R1, proj, R0);
  fm_kernel<<<gF, blk, 0, stream>>>(R2, proj, R1);

  // 7. kv, ksum from kf(R1), v(R3)
  kv_kernel<<<dim3(Bc * Hc), blk, 0, stream>>>(R1, R3, kvb, ksb);

  // 8. attn from qf(R0) -> R2
  attn_kernel<<<gF, blk, 0, stream>>>(R0, kvb, ksb, R2);

  // 9. x2 = x + attn @ wo + bo -> d_out (f32)
  mgemm_kernel<1><<<gD, blk, 0, stream>>>((const ushort*)R2, (const ushort*)wot, bo, x,
                                          out, nullptr, TOK, Dc, Dc, Dc, Dc);

  // 10. h2 = LN2(x2) -> R0
  ln_kernel<<<dim3(TOK), blk, 0, stream>>>(out, ln2_g, ln2_b, R0);

  // 11-12. FFN in two DFF halves (mid aliases R1+R2)
  dim3 gW1(2048 / 128, TOK / 128);
  // half 0
  mgemm_kernel<2><<<gW1, blk, 0, stream>>>((const ushort*)R0, (const ushort*)w1t, b1, nullptr,
                                           nullptr, mid, TOK, 2048, Dc, Dc, Dc);
  mgemm_kernel<3><<<gD, blk, 0, stream>>>((const ushort*)mid, (const ushort*)w2t, b2, out,
                                          out, nullptr, TOK, Dc, 2048, 2048, DFFc);
  // half 1
  mgemm_kernel<2><<<gW1, blk, 0, stream>>>((const ushort*)R0, (const ushort*)(w1t + (size_t)2048 * Dc), b1 + 2048,
                                           nullptr, nullptr, mid, TOK, 2048, Dc, Dc, Dc);
  mgemm_kernel<3><<<gD, blk, 0, stream>>>((const ushort*)mid, (const ushort*)(w2t + 2048), nullptr, out,
                                          out, nullptr, TOK, Dc, 2048, 2048, DFFc);
}

// Round 4
// 1298.655 us; speedup vs baseline: 7.1094x; 1.8395x over previous
//
#include <hip/hip_runtime.h>
#include <hip/hip_bf16.h>
#include <math.h>

using bf16 = __hip_bfloat16;
typedef __attribute__((ext_vector_type(8))) short short8;
typedef __attribute__((ext_vector_type(4))) float f32x4;

constexpr int Bc = 4, Sc = 4096, Dc = 1024, Hc = 16, DHc = 64, Fc = 64, DFFc = 4096;
constexpr float EPS_LN_C = 1e-5f, EPS_ATTN_C = 1e-6f;
constexpr int KVSPLIT = 16;   // S-splits for kv reduction

static __device__ __forceinline__ float b2f(bf16 v) { return __bfloat162float(v); }
static __device__ __forceinline__ bf16 f2b(float f) { return __float2bfloat16(f); }

// ---------------- block reduction (256 threads, wave64) ----------------
__device__ float block_reduce_sum(float v) {
  __shared__ float red[4];
  int lane = threadIdx.x & 63, wid = threadIdx.x >> 6;
#pragma unroll
  for (int off = 32; off > 0; off >>= 1) v += __shfl_down(v, off, 64);
  __syncthreads();
  if (lane == 0) red[wid] = v;
  __syncthreads();
  return red[0] + red[1] + red[2] + red[3];
}

// ---------------- LayerNorm: one block per row (D=1024) ----------------
__global__ void ln_kernel(const float* __restrict__ x, const float* __restrict__ g,
                          const float* __restrict__ bta, bf16* __restrict__ out) {
  int row = blockIdx.x;
  const float* xr = x + (size_t)row * Dc;
  int t = threadIdx.x;
  float v[4];
#pragma unroll
  for (int i = 0; i < 4; ++i) v[i] = xr[t + 256 * i];
  float s = block_reduce_sum(v[0] + v[1] + v[2] + v[3]);
  float mu = s * (1.f / Dc);
  float vs = 0.f;
#pragma unroll
  for (int i = 0; i < 4; ++i) { float d = v[i] - mu; vs += d * d; }
  vs = block_reduce_sum(vs);
  float rstd = rsqrtf(vs * (1.f / Dc) + EPS_LN_C);
  bf16* orow = out + (size_t)row * Dc;
#pragma unroll
  for (int i = 0; i < 4; ++i) {
    int c = t + 256 * i;
    orow[c] = f2b((v[i] - mu) * rstd * g[c] + bta[c]);
  }
}

// ------------- transpose + convert: in f32 [K,N] -> out bf16 [N,K] -------------
__global__ void tcvt_kernel(const float* __restrict__ in, bf16* __restrict__ out,
                            int K, int N) {
  __shared__ float t[32][33];
  int n0 = blockIdx.x * 32, k0 = blockIdx.y * 32;
  int tid = threadIdx.x;
#pragma unroll
  for (int i = 0; i < 4; ++i) {
    int idx = tid + 256 * i;
    int r = idx >> 5, c = idx & 31;
    t[r][c] = in[(size_t)(k0 + r) * N + n0 + c];
  }
  __syncthreads();
#pragma unroll
  for (int i = 0; i < 4; ++i) {
    int idx = tid + 256 * i;
    int r = idx >> 5, c = idx & 31;
    out[(size_t)(n0 + r) * K + k0 + c] = f2b(t[c][r]);
  }
}

// ---------------- MFMA GEMM: C[M,N] = A(bf16)[M,lda] * Bt(bf16)[N,ldbt]^T ----------------
// 128x128 tile, BK=32, 4 waves each 64x64 (4x4 mfma_f32_16x16x32_bf16).
template <int EPI>
__global__ __launch_bounds__(256, 2)
void mgemm_kernel(const ushort* __restrict__ A, const ushort* __restrict__ Bt,
                  const float* __restrict__ bias, const float* __restrict__ res,
                  float* __restrict__ outF, bf16* __restrict__ outB,
                  int M, int N, int K, int lda, int ldbt) {
  __shared__ ushort As[128 * 32];
  __shared__ ushort Bs[128 * 32];
  int tid = threadIdx.x;
  int wave = tid >> 6, lane = tid & 63;
  int row0 = blockIdx.y * 128, col0 = blockIdx.x * 128;
  int wm = (wave >> 1) * 64, wn = (wave & 1) * 64;
  int mrow = lane & 15, quad = lane >> 4;

  f32x4 acc[4][4] = {};

  int c0 = tid, c1 = tid + 256;
  const ushort* aP0 = A + (size_t)(row0 + (c0 >> 2)) * lda + (c0 & 3) * 8;
  const ushort* aP1 = A + (size_t)(row0 + (c1 >> 2)) * lda + (c1 & 3) * 8;
  const ushort* bP0 = Bt + (size_t)(col0 + (c0 >> 2)) * ldbt + (c0 & 3) * 8;
  const ushort* bP1 = Bt + (size_t)(col0 + (c1 >> 2)) * ldbt + (c1 & 3) * 8;
  ushort* aL0 = As + c0 * 8;
  ushort* aL1 = As + c1 * 8;
  ushort* bL0 = Bs + c0 * 8;
  ushort* bL1 = Bs + c1 * 8;

  for (int k0 = 0; k0 < K; k0 += 32) {
    __syncthreads();
    __builtin_amdgcn_global_load_lds((const __attribute__((address_space(1))) void*)aP0,
                                     (__attribute__((address_space(3))) void*)aL0, 16, 0, 0);
    __builtin_amdgcn_global_load_lds((const __attribute__((address_space(1))) void*)aP1,
                                     (__attribute__((address_space(3))) void*)aL1, 16, 0, 0);
    __builtin_amdgcn_global_load_lds((const __attribute__((address_space(1))) void*)bP0,
                                     (__attribute__((address_space(3))) void*)bL0, 16, 0, 0);
    __builtin_amdgcn_global_load_lds((const __attribute__((address_space(1))) void*)bP1,
                                     (__attribute__((address_space(3))) void*)bL1, 16, 0, 0);
    aP0 += 32; aP1 += 32; bP0 += 32; bP1 += 32;
    __syncthreads();

    short8 af[4], bfv[4];
#pragma unroll
    for (int i = 0; i < 4; ++i)
      af[i] = *(const short8*)(As + (wm + i * 16 + mrow) * 32 + quad * 8);
#pragma unroll
    for (int j = 0; j < 4; ++j)
      bfv[j] = *(const short8*)(Bs + (wn + j * 16 + mrow) * 32 + quad * 8);
#pragma unroll
    for (int i = 0; i < 4; ++i)
#pragma unroll
      for (int j = 0; j < 4; ++j)
        acc[i][j] = __builtin_amdgcn_mfma_f32_16x16x32_bf16(af[i], bfv[j], acc[i][j], 0, 0, 0);
  }

#pragma unroll
  for (int i = 0; i < 4; ++i) {
#pragma unroll
    for (int j = 0; j < 4; ++j) {
      int rb = row0 + wm + i * 16 + quad * 4;
      int c = col0 + wn + j * 16 + mrow;
#pragma unroll
      for (int r = 0; r < 4; ++r) {
        int rr = rb + r;
        float v = acc[i][j][r];
        if (EPI == 1 || EPI == 2) v += bias[c];
        if (EPI == 3) { if (bias) v += bias[c]; }
        if (EPI == 2) v = 0.5f * v * (1.f + erff(v * 0.70710678118654752f));
        if (EPI == 1 || EPI == 3) v += res[(size_t)rr * N + c];
        if (EPI == 0 || EPI == 2) outB[(size_t)rr * N + c] = f2b(v);
        else outF[(size_t)rr * N + c] = v;
      }
    }
  }
}

// ---------------- feature map: per head, [S,DH] @ proj[DH,F], relu + eps ----------------
__global__ void fm_kernel(const bf16* __restrict__ qin, const float* __restrict__ proj,
                          bf16* __restrict__ qf) {
  __shared__ float pj[64][65];
  __shared__ float qs[64][65];
  int t = threadIdx.x;
  int b = blockIdx.z, h = blockIdx.y, s0 = blockIdx.x * 64;
#pragma unroll
  for (int i = 0; i < 16; ++i) {
    int idx = t + 256 * i;
    pj[idx >> 6][idx & 63] = proj[idx];
    int sl = idx >> 6, d = idx & 63;
    qs[sl][d] = b2f(qin[((size_t)(b * Sc + s0 + sl)) * (Hc * DHc) + h * DHc + d]);
  }
  __syncthreads();
  size_t obase = (((size_t)(b * Hc + h)) * Sc + s0) * Fc;
#pragma unroll
  for (int i = 0; i < 16; ++i) {
    int idx = t + 256 * i;
    int sl = idx >> 6, f = idx & 63;
    float acc = 0.f;
#pragma unroll 8
    for (int d = 0; d < 64; ++d) acc += qs[sl][d] * pj[d][f];
    acc = fmaxf(acc, 0.f) + EPS_ATTN_C;
    qf[obase + (size_t)sl * Fc + f] = f2b(acc);
  }
}

// ------- kv partial: grid (KVSPLIT, B*H); each block reduces Sc/KVSPLIT rows -------
__global__ void kvp_kernel(const bf16* __restrict__ kf, const bf16* __restrict__ v,
                           float* __restrict__ kvp, float* __restrict__ ksump) {
  int split = blockIdx.x, bh = blockIdx.y;
  int b = bh >> 4, h = bh & 15;
  __shared__ float ks[64][65];
  __shared__ float vs[64][65];
  int t = threadIdx.x;
  int f = t & 63, dg = t >> 6;
  float acc[16] = {};
  float sacc = 0.f;
  int s_begin = split * (Sc / KVSPLIT), s_end = s_begin + Sc / KVSPLIT;
  for (int s0 = s_begin; s0 < s_end; s0 += 64) {
#pragma unroll
    for (int i = 0; i < 16; ++i) {
      int idx = t + 256 * i;
      int sl = idx >> 6, c = idx & 63;
      ks[sl][c] = b2f(kf[(((size_t)bh * Sc) + s0 + sl) * Fc + c]);
      vs[sl][c] = b2f(v[((size_t)(b * Sc + s0 + sl)) * (Hc * DHc) + h * DHc + c]);
    }
    __syncthreads();
#pragma unroll 4
    for (int sl = 0; sl < 64; ++sl) {
      float kval = ks[sl][f];
      if (dg == 0) sacc += kval;
#pragma unroll
      for (int j = 0; j < 16; ++j) acc[j] += kval * vs[sl][dg * 16 + j];
    }
    __syncthreads();
  }
  size_t pbase = (size_t)bh * KVSPLIT + split;
#pragma unroll
  for (int j = 0; j < 16; ++j) kvp[(pbase * 64 + f) * 64 + dg * 16 + j] = acc[j];
  if (dg == 0) ksump[pbase * 64 + f] = sacc;
}

// ------- kv reduce: grid (B*H); sums KVSPLIT partials -------
__global__ void kvr_kernel(const float* __restrict__ kvp, const float* __restrict__ ksump,
                           float* __restrict__ kv, float* __restrict__ ksum) {
  int bh = blockIdx.x;
  int t = threadIdx.x;
#pragma unroll
  for (int i = 0; i < 16; ++i) {
    int idx = t + 256 * i;
    float s = 0.f;
#pragma unroll
    for (int j = 0; j < KVSPLIT; ++j)
      s += kvp[((size_t)bh * KVSPLIT + j) * 4096 + idx];
    kv[(size_t)bh * 4096 + idx] = s;
  }
  if (t < 64) {
    float s = 0.f;
#pragma unroll
    for (int j = 0; j < KVSPLIT; ++j)
      s += ksump[((size_t)bh * KVSPLIT + j) * 64 + t];
    ksum[bh * 64 + t] = s;
  }
}

// ---------------- attn = (qf @ kv) / (qf . ksum + eps) ----------------
__global__ void attn_kernel(const bf16* __restrict__ qf, const float* __restrict__ kv,
                            const float* __restrict__ ksum, bf16* __restrict__ attn) {
  int b = blockIdx.z, h = blockIdx.y, s0 = blockIdx.x * 64;
  int bh = b * Hc + h;
  __shared__ float kvs[64][65];
  __shared__ float qs[64][65];
  __shared__ float kss[64];
  int t = threadIdx.x;
#pragma unroll
  for (int i = 0; i < 16; ++i) {
    int idx = t + 256 * i;
    kvs[idx >> 6][idx & 63] = kv[(size_t)bh * 4096 + idx];
    int sl = idx >> 6, f = idx & 63;
    qs[sl][f] = b2f(qf[(((size_t)bh * Sc) + s0 + sl) * Fc + f]);
  }
  if (t < 64) kss[t] = ksum[bh * 64 + t];
  __syncthreads();
  int sl = t & 63, dg = t >> 6;
  float den = EPS_ATTN_C;
#pragma unroll 8
  for (int f = 0; f < 64; ++f) den += qs[sl][f] * kss[f];
  float inv = 1.0f / den;
  size_t orow = ((size_t)(b * Sc + s0 + sl)) * (Hc * DHc) + h * DHc;
#pragma unroll
  for (int j = 0; j < 16; ++j) {
    int d = dg * 16 + j;
    float acc = 0.f;
#pragma unroll 8
    for (int f = 0; f < 64; ++f) acc += qs[sl][f] * kvs[f][d];
    attn[orow + d] = f2b(acc * inv);
  }
}

extern "C" void kernel_launch(void* const* d_in, const int* in_sizes, int n_in,
                              void* d_out, int out_size, void* d_ws, size_t ws_size,
                              hipStream_t stream) {
  const float* x     = (const float*)d_in[0];
  const float* ln1_g = (const float*)d_in[1];
  const float* ln1_b = (const float*)d_in[2];
  const float* wq    = (const float*)d_in[3];
  const float* wk    = (const float*)d_in[4];
  const float* wv    = (const float*)d_in[5];
  const float* proj  = (const float*)d_in[6];
  const float* wo    = (const float*)d_in[7];
  const float* bo    = (const float*)d_in[8];
  const float* ln2_g = (const float*)d_in[9];
  const float* ln2_b = (const float*)d_in[10];
  const float* w1    = (const float*)d_in[11];
  const float* b1    = (const float*)d_in[12];
  const float* w2    = (const float*)d_in[13];
  const float* b2    = (const float*)d_in[14];
  float* out = (float*)d_out;
  (void)ws_size; (void)in_sizes; (void)n_in; (void)out_size;

  // ---- workspace plan (peak ~153 MB) ----
  const size_t TOK = (size_t)Bc * Sc;           // 16384
  const size_t REG = TOK * Dc * sizeof(bf16);   // 32 MB
  char* ws = (char*)d_ws;
  bf16* R0 = (bf16*)(ws + 0 * REG);             // h -> qf -> h2
  bf16* R1 = (bf16*)(ws + 1 * REG);             // q -> kf -> mid(lo)
  bf16* R2 = (bf16*)(ws + 2 * REG);             // k -> [kv partials] -> attn -> mid(hi)
  bf16* R3 = (bf16*)(ws + 3 * REG);             // v
  bf16* mid = R1;                               // TOK x 2048 bf16 spans R1+R2
  // kv partials alias R2 (k is dead after fm; attn written only after kvr):
  float* kvpart = (float*)R2;                                   // 16 MB
  float* kspart = (float*)((char*)R2 + (size_t)64 * KVSPLIT * 4096 * 4);  // 256 KB
  char* p = ws + 4 * REG;
  float* kvb = (float*)p;                 p += (size_t)Bc * Hc * Fc * DHc * 4;   // 1 MB
  float* ksb = (float*)p;                 p += (size_t)Bc * Hc * Fc * 4;         // 16 KB
  bf16* wqt = (bf16*)p;                   p += (size_t)Dc * Dc * 2;              // 2 MB
  bf16* wkt = (bf16*)p;                   p += (size_t)Dc * Dc * 2;
  bf16* wvt = (bf16*)p;                   p += (size_t)Dc * Dc * 2;
  bf16* wot = (bf16*)p;                   p += (size_t)Dc * Dc * 2;
  bf16* w1t = (bf16*)p;                   p += (size_t)Dc * DFFc * 2;            // 8 MB
  bf16* w2t = (bf16*)p;                   p += (size_t)Dc * DFFc * 2;            // 8 MB

  dim3 blk(256);
  // 0. transpose+convert weights to bf16 B^T form
  tcvt_kernel<<<dim3(Dc / 32, Dc / 32), blk, 0, stream>>>(wq, wqt, Dc, Dc);
  tcvt_kernel<<<dim3(Dc / 32, Dc / 32), blk, 0, stream>>>(wk, wkt, Dc, Dc);
  tcvt_kernel<<<dim3(Dc / 32, Dc / 32), blk, 0, stream>>>(wv, wvt, Dc, Dc);
  tcvt_kernel<<<dim3(Dc / 32, Dc / 32), blk, 0, stream>>>(wo, wot, Dc, Dc);
  tcvt_kernel<<<dim3(DFFc / 32, Dc / 32), blk, 0, stream>>>(w1, w1t, Dc, DFFc);
  tcvt_kernel<<<dim3(Dc / 32, DFFc / 32), blk, 0, stream>>>(w2, w2t, DFFc, Dc);

  // 1. h = LN1(x) -> R0
  ln_kernel<<<dim3(TOK), blk, 0, stream>>>(x, ln1_g, ln1_b, R0);

  // 2-4. q,k,v = h @ {wq,wk,wv}  (MFMA)
  dim3 gD(Dc / 128, TOK / 128);
  mgemm_kernel<0><<<gD, blk, 0, stream>>>((const ushort*)R0, (const ushort*)wqt, nullptr, nullptr,
                                          nullptr, R1, TOK, Dc, Dc, Dc, Dc);
  mgemm_kernel<0><<<gD, blk, 0, stream>>>((const ushort*)R0, (const ushort*)wkt, nullptr, nullptr,
                                          nullptr, R2, TOK, Dc, Dc, Dc, Dc);
  mgemm_kernel<0><<<gD, blk, 0, stream>>>((const ushort*)R0, (const ushort*)wvt, nullptr, nullptr,
                                          nullptr, R3, TOK, Dc, Dc, Dc, Dc);

  // 5-6. qf = fm(q): R1 -> R0 ; kf = fm(k): R2 -> R1   (k consumed before kvpart aliases R2)
  dim3 gF(Sc / 64, Hc, Bc);
  fm_kernel<<<gF, blk, 0, stream>>>(R1, proj, R0);
  fm_kernel<<<gF, blk, 0, stream>>>(R2, proj, R1);

  // 7. kv partials (split-K over S) + reduce
  kvp_kernel<<<dim3(KVSPLIT, Bc * Hc), blk, 0, stream>>>(R1, R3, kvpart, kspart);
  kvr_kernel<<<dim3(Bc * Hc), blk, 0, stream>>>(kvpart, kspart, kvb, ksb);

  // 8. attn from qf(R0) -> R2 (partials dead after kvr)
  attn_kernel<<<gF, blk, 0, stream>>>(R0, kvb, ksb, R2);

  // 9. x2 = x + attn @ wo + bo -> d_out (f32)
  mgemm_kernel<1><<<gD, blk, 0, stream>>>((const ushort*)R2, (const ushort*)wot, bo, x,
                                          out, nullptr, TOK, Dc, Dc, Dc, Dc);

  // 10. h2 = LN2(x2) -> R0
  ln_kernel<<<dim3(TOK), blk, 0, stream>>>(out, ln2_g, ln2_b, R0);

  // 11-12. FFN in two DFF halves (mid aliases R1+R2)
  dim3 gW1(2048 / 128, TOK / 128);
  mgemm_kernel<2><<<gW1, blk, 0, stream>>>((const ushort*)R0, (const ushort*)w1t, b1, nullptr,
                                           nullptr, mid, TOK, 2048, Dc, Dc, Dc);
  mgemm_kernel<3><<<gD, blk, 0, stream>>>((const ushort*)mid, (const ushort*)w2t, b2, out,
                                          out, nullptr, TOK, Dc, 2048, 2048, DFFc);
  mgemm_kernel<2><<<gW1, blk, 0, stream>>>((const ushort*)R0, (const ushort*)(w1t + (size_t)2048 * Dc), b1 + 2048,
                                           nullptr, nullptr, mid, TOK, 2048, Dc, Dc, Dc);
  mgemm_kernel<3><<<gD, blk, 0, stream>>>((const ushort*)mid, (const ushort*)(w2t + 2048), nullptr, out,
                                          out, nullptr, TOK, Dc, 2048, 2048, DFFc);
}

// Round 5
// 902.509 us; speedup vs baseline: 10.2301x; 1.4389x over previous
//
#include <hip/hip_runtime.h>
#include <hip/hip_bf16.h>
#include <math.h>

using bf16 = __hip_bfloat16;
typedef __attribute__((ext_vector_type(8))) short short8;
typedef __attribute__((ext_vector_type(4))) float f32x4;

constexpr int Bc = 4, Sc = 4096, Dc = 1024, Hc = 16, DHc = 64, Fc = 64, DFFc = 4096;
constexpr float EPS_LN_C = 1e-5f, EPS_ATTN_C = 1e-6f;
constexpr int KVSPLIT = 16;

static __device__ __forceinline__ float b2f(bf16 v) { return __bfloat162float(v); }
static __device__ __forceinline__ bf16 f2b(float f) { return __float2bfloat16(f); }

// ---------------- block reduction (256 threads, wave64) ----------------
__device__ float block_reduce_sum(float v) {
  __shared__ float red[4];
  int lane = threadIdx.x & 63, wid = threadIdx.x >> 6;
#pragma unroll
  for (int off = 32; off > 0; off >>= 1) v += __shfl_down(v, off, 64);
  __syncthreads();
  if (lane == 0) red[wid] = v;
  __syncthreads();
  return red[0] + red[1] + red[2] + red[3];
}

// ---------------- LayerNorm: one block per row (D=1024) ----------------
__global__ void ln_kernel(const float* __restrict__ x, const float* __restrict__ g,
                          const float* __restrict__ bta, bf16* __restrict__ out) {
  int row = blockIdx.x;
  const float* xr = x + (size_t)row * Dc;
  int t = threadIdx.x;
  float v[4];
#pragma unroll
  for (int i = 0; i < 4; ++i) v[i] = xr[t + 256 * i];
  float s = block_reduce_sum(v[0] + v[1] + v[2] + v[3]);
  float mu = s * (1.f / Dc);
  float vs = 0.f;
#pragma unroll
  for (int i = 0; i < 4; ++i) { float d = v[i] - mu; vs += d * d; }
  vs = block_reduce_sum(vs);
  float rstd = rsqrtf(vs * (1.f / Dc) + EPS_LN_C);
  bf16* orow = out + (size_t)row * Dc;
#pragma unroll
  for (int i = 0; i < 4; ++i) {
    int c = t + 256 * i;
    orow[c] = f2b((v[i] - mu) * rstd * g[c] + bta[c]);
  }
}

// ------------- transpose + convert: in f32 [K,N] -> out bf16 [N,K] -------------
__global__ void tcvt_kernel(const float* __restrict__ in, bf16* __restrict__ out,
                            int K, int N) {
  __shared__ float t[32][33];
  int n0 = blockIdx.x * 32, k0 = blockIdx.y * 32;
  int tid = threadIdx.x;
#pragma unroll
  for (int i = 0; i < 4; ++i) {
    int idx = tid + 256 * i;
    int r = idx >> 5, c = idx & 31;
    t[r][c] = in[(size_t)(k0 + r) * N + n0 + c];
  }
  __syncthreads();
#pragma unroll
  for (int i = 0; i < 4; ++i) {
    int idx = tid + 256 * i;
    int r = idx >> 5, c = idx & 31;
    out[(size_t)(n0 + r) * K + k0 + c] = f2b(t[c][r]);
  }
}

// ---------------- MFMA GEMM: C[M,N] = A(bf16)[M,lda] * Bt(bf16)[N,ldbt]^T ----------------
template <int EPI>
__global__ __launch_bounds__(256, 2)
void mgemm_kernel(const ushort* __restrict__ A, const ushort* __restrict__ Bt,
                  const float* __restrict__ bias, const float* __restrict__ res,
                  float* __restrict__ outF, bf16* __restrict__ outB,
                  int M, int N, int K, int lda, int ldbt) {
  __shared__ ushort As[128 * 32];
  __shared__ ushort Bs[128 * 32];
  int tid = threadIdx.x;
  int wave = tid >> 6, lane = tid & 63;
  int row0 = blockIdx.y * 128, col0 = blockIdx.x * 128;
  int wm = (wave >> 1) * 64, wn = (wave & 1) * 64;
  int mrow = lane & 15, quad = lane >> 4;

  f32x4 acc[4][4] = {};

  int c0 = tid, c1 = tid + 256;
  const ushort* aP0 = A + (size_t)(row0 + (c0 >> 2)) * lda + (c0 & 3) * 8;
  const ushort* aP1 = A + (size_t)(row0 + (c1 >> 2)) * lda + (c1 & 3) * 8;
  const ushort* bP0 = Bt + (size_t)(col0 + (c0 >> 2)) * ldbt + (c0 & 3) * 8;
  const ushort* bP1 = Bt + (size_t)(col0 + (c1 >> 2)) * ldbt + (c1 & 3) * 8;
  ushort* aL0 = As + c0 * 8;
  ushort* aL1 = As + c1 * 8;
  ushort* bL0 = Bs + c0 * 8;
  ushort* bL1 = Bs + c1 * 8;

  for (int k0 = 0; k0 < K; k0 += 32) {
    __syncthreads();
    __builtin_amdgcn_global_load_lds((const __attribute__((address_space(1))) void*)aP0,
                                     (__attribute__((address_space(3))) void*)aL0, 16, 0, 0);
    __builtin_amdgcn_global_load_lds((const __attribute__((address_space(1))) void*)aP1,
                                     (__attribute__((address_space(3))) void*)aL1, 16, 0, 0);
    __builtin_amdgcn_global_load_lds((const __attribute__((address_space(1))) void*)bP0,
                                     (__attribute__((address_space(3))) void*)bL0, 16, 0, 0);
    __builtin_amdgcn_global_load_lds((const __attribute__((address_space(1))) void*)bP1,
                                     (__attribute__((address_space(3))) void*)bL1, 16, 0, 0);
    aP0 += 32; aP1 += 32; bP0 += 32; bP1 += 32;
    __syncthreads();

    short8 af[4], bfv[4];
#pragma unroll
    for (int i = 0; i < 4; ++i)
      af[i] = *(const short8*)(As + (wm + i * 16 + mrow) * 32 + quad * 8);
#pragma unroll
    for (int j = 0; j < 4; ++j)
      bfv[j] = *(const short8*)(Bs + (wn + j * 16 + mrow) * 32 + quad * 8);
#pragma unroll
    for (int i = 0; i < 4; ++i)
#pragma unroll
      for (int j = 0; j < 4; ++j)
        acc[i][j] = __builtin_amdgcn_mfma_f32_16x16x32_bf16(af[i], bfv[j], acc[i][j], 0, 0, 0);
  }

#pragma unroll
  for (int i = 0; i < 4; ++i) {
#pragma unroll
    for (int j = 0; j < 4; ++j) {
      int rb = row0 + wm + i * 16 + quad * 4;
      int c = col0 + wn + j * 16 + mrow;
#pragma unroll
      for (int r = 0; r < 4; ++r) {
        int rr = rb + r;
        float v = acc[i][j][r];
        if (EPI == 1 || EPI == 2) v += bias[c];
        if (EPI == 3) { if (bias) v += bias[c]; }
        if (EPI == 2) v = 0.5f * v * (1.f + erff(v * 0.70710678118654752f));
        if (EPI == 1 || EPI == 3) v += res[(size_t)rr * N + c];
        if (EPI == 0 || EPI == 2) outB[(size_t)rr * N + c] = f2b(v);
        else outF[(size_t)rr * N + c] = v;
      }
    }
  }
}

// ======== fm_mfma: per-head [256s x 64] @ projT[64f][64d]^T, relu+eps ========
// grid (S/256, H, B). in: [B,S,H*DH] bf16 (lda=1024). out: [B,H,S,F] bf16.
__global__ __launch_bounds__(256, 2)
void fm_mfma(const ushort* __restrict__ qin, const ushort* __restrict__ pjt,
             bf16* __restrict__ qf) {
  __shared__ ushort As[256 * 64];   // [s_local][d]
  __shared__ ushort Bs[64 * 64];    // [f][d]
  int t = threadIdx.x;
  int wave = t >> 6, lane = t & 63;
  int mrow = lane & 15, quad = lane >> 4;
  int b = blockIdx.z, h = blockIdx.y, s0 = blockIdx.x * 256;
  const ushort* abase = qin + ((size_t)b * Sc + s0) * (Hc * DHc) + h * DHc;

#pragma unroll
  for (int i = 0; i < 8; ++i) {
    int c = t + 256 * i;       // 2048 chunks of 8 elems
    int row = c >> 3, col = (c & 7) * 8;
    __builtin_amdgcn_global_load_lds(
        (const __attribute__((address_space(1))) void*)(abase + (size_t)row * (Hc * DHc) + col),
        (__attribute__((address_space(3))) void*)(As + c * 8), 16, 0, 0);
  }
#pragma unroll
  for (int i = 0; i < 2; ++i) {
    int c = t + 256 * i;       // 512 chunks
    __builtin_amdgcn_global_load_lds(
        (const __attribute__((address_space(1))) void*)(pjt + c * 8),
        (__attribute__((address_space(3))) void*)(Bs + c * 8), 16, 0, 0);
  }
  __syncthreads();

  f32x4 acc[4][4] = {};
#pragma unroll
  for (int step = 0; step < 2; ++step) {
    short8 af[4], bfv[4];
#pragma unroll
    for (int i = 0; i < 4; ++i)
      af[i] = *(const short8*)(As + (wave * 64 + i * 16 + mrow) * 64 + quad * 8 + step * 32);
#pragma unroll
    for (int j = 0; j < 4; ++j)
      bfv[j] = *(const short8*)(Bs + (j * 16 + mrow) * 64 + quad * 8 + step * 32);
#pragma unroll
    for (int i = 0; i < 4; ++i)
#pragma unroll
      for (int j = 0; j < 4; ++j)
        acc[i][j] = __builtin_amdgcn_mfma_f32_16x16x32_bf16(af[i], bfv[j], acc[i][j], 0, 0, 0);
  }

  size_t obase = ((size_t)(b * Hc + h)) * Sc + s0;
#pragma unroll
  for (int i = 0; i < 4; ++i) {
#pragma unroll
    for (int j = 0; j < 4; ++j) {
      int f = j * 16 + mrow;
#pragma unroll
      for (int r = 0; r < 4; ++r) {
        int s = wave * 64 + i * 16 + quad * 4 + r;
        float v = fmaxf(acc[i][j][r], 0.f) + EPS_ATTN_C;
        qf[(obase + s) * Fc + f] = f2b(v);
      }
    }
  }
}

// ======== kvp_mfma: split-K kf^T v (+ ksum) via LDS transpose ========
// grid (KVSPLIT, B*H). kf: [B,H,S,F] bf16; v: [B,S,H*DH] bf16.
__global__ __launch_bounds__(256, 2)
void kvp_mfma(const ushort* __restrict__ kf, const ushort* __restrict__ v,
              float* __restrict__ kvp, float* __restrict__ ksump) {
  constexpr int LT = 72;  // padded stride (144 B, 16B-aligned)
  __shared__ ushort kfT[64 * LT];   // [f][s]
  __shared__ ushort vT[64 * LT];    // [d][s]
  int t = threadIdx.x;
  int wave = t >> 6, lane = t & 63;
  int mrow = lane & 15, quad = lane >> 4;
  int split = blockIdx.x, bh = blockIdx.y;
  int b = bh >> 4, h = bh & 15;
  int sbase = split * (Sc / KVSPLIT);

  short8 ones, zero;
#pragma unroll
  for (int i = 0; i < 8; ++i) { ones[i] = (short)0x3F80; zero[i] = 0; }
  short8 bks = (mrow == 0) ? ones : zero;

  f32x4 acc[4] = {};
  f32x4 accks = {};

  for (int sc = 0; sc < Sc / KVSPLIT; sc += 64) {
    __syncthreads();
    int sl = t >> 2, c8 = (t & 3) * 8;
    const ushort* kp = kf + (((size_t)bh * Sc) + sbase + sc + sl) * Fc + c8;
    const ushort* vp = v + (((size_t)b * Sc) + sbase + sc + sl) * (Hc * DHc) + h * DHc + c8;
#pragma unroll
    for (int half = 0; half < 2; ++half) {
      short8 kv8 = *(const short8*)(kp + half * 32);
      short8 vv8 = *(const short8*)(vp + half * 32);
#pragma unroll
      for (int jj = 0; jj < 8; ++jj) {
        kfT[(c8 + half * 32 + jj) * LT + sl] = (ushort)kv8[jj];
        vT[(c8 + half * 32 + jj) * LT + sl] = (ushort)vv8[jj];
      }
    }
    __syncthreads();
#pragma unroll
    for (int step = 0; step < 2; ++step) {
      short8 af = *(const short8*)(kfT + (wave * 16 + mrow) * LT + quad * 8 + step * 32);
      short8 bfv[4];
#pragma unroll
      for (int j = 0; j < 4; ++j)
        bfv[j] = *(const short8*)(vT + (j * 16 + mrow) * LT + quad * 8 + step * 32);
#pragma unroll
      for (int j = 0; j < 4; ++j)
        acc[j] = __builtin_amdgcn_mfma_f32_16x16x32_bf16(af, bfv[j], acc[j], 0, 0, 0);
      accks = __builtin_amdgcn_mfma_f32_16x16x32_bf16(af, bks, accks, 0, 0, 0);
    }
  }

  size_t pbase = (size_t)bh * KVSPLIT + split;
#pragma unroll
  for (int j = 0; j < 4; ++j) {
    int d = j * 16 + mrow;
#pragma unroll
    for (int r = 0; r < 4; ++r) {
      int f = wave * 16 + quad * 4 + r;
      kvp[(pbase * 64 + f) * 64 + d] = acc[j][r];
    }
  }
  if (mrow == 0) {
#pragma unroll
    for (int r = 0; r < 4; ++r) {
      int f = wave * 16 + quad * 4 + r;
      ksump[pbase * 64 + f] = accks[r];
    }
  }
}

// ------- kv reduce: sums KVSPLIT partials -> kvt bf16 [d][f], ksum bf16 -------
__global__ void kvr_kernel(const float* __restrict__ kvp, const float* __restrict__ ksump,
                           bf16* __restrict__ kvt, bf16* __restrict__ ksum16) {
  int bh = blockIdx.x;
  int t = threadIdx.x;
#pragma unroll
  for (int i = 0; i < 16; ++i) {
    int idx = t + 256 * i;
    int f = idx >> 6, d = idx & 63;
    float s = 0.f;
#pragma unroll
    for (int j = 0; j < KVSPLIT; ++j)
      s += kvp[((size_t)bh * KVSPLIT + j) * 4096 + idx];
    kvt[((size_t)bh * 64 + d) * 64 + f] = f2b(s);
  }
  if (t < 64) {
    float s = 0.f;
#pragma unroll
    for (int j = 0; j < KVSPLIT; ++j)
      s += ksump[((size_t)bh * KVSPLIT + j) * 64 + t];
    ksum16[bh * 64 + t] = f2b(s);
  }
}

// ======== attn_mfma: per-head (qf @ kv) / (qf.ksum + eps) ========
// grid (S/256, H, B). qf: [B,H,S,F] bf16; kvt: [bh][d][f] bf16; out: [B,S,H*DH] bf16.
__global__ __launch_bounds__(256, 2)
void attn_mfma(const ushort* __restrict__ qf, const ushort* __restrict__ kvt,
               const ushort* __restrict__ ksum16, bf16* __restrict__ attn) {
  __shared__ ushort As[256 * 64];   // [s_local][f]
  __shared__ ushort Bs[64 * 64];    // [d][f]
  int t = threadIdx.x;
  int wave = t >> 6, lane = t & 63;
  int mrow = lane & 15, quad = lane >> 4;
  int b = blockIdx.z, h = blockIdx.y, s0 = blockIdx.x * 256;
  int bh = b * Hc + h;
  const ushort* abase = qf + (((size_t)bh * Sc) + s0) * Fc;
  const ushort* bbase = kvt + (size_t)bh * 4096;

#pragma unroll
  for (int i = 0; i < 8; ++i) {
    int c = t + 256 * i;
    __builtin_amdgcn_global_load_lds(
        (const __attribute__((address_space(1))) void*)(abase + c * 8),
        (__attribute__((address_space(3))) void*)(As + c * 8), 16, 0, 0);
  }
#pragma unroll
  for (int i = 0; i < 2; ++i) {
    int c = t + 256 * i;
    __builtin_amdgcn_global_load_lds(
        (const __attribute__((address_space(1))) void*)(bbase + c * 8),
        (__attribute__((address_space(3))) void*)(Bs + c * 8), 16, 0, 0);
  }
  // ksum B-fragment: row n=0 holds ksum, other rows zero
  short8 zero;
#pragma unroll
  for (int i = 0; i < 8; ++i) zero[i] = 0;
  short8 ksf[2];
#pragma unroll
  for (int step = 0; step < 2; ++step) {
    short8 kv8 = *(const short8*)(ksum16 + bh * 64 + quad * 8 + step * 32);
    ksf[step] = (mrow == 0) ? kv8 : zero;
  }
  __syncthreads();

  f32x4 acc[4][4] = {};
  f32x4 accd[4] = {};
#pragma unroll
  for (int step = 0; step < 2; ++step) {
    short8 af[4], bfv[4];
#pragma unroll
    for (int i = 0; i < 4; ++i)
      af[i] = *(const short8*)(As + (wave * 64 + i * 16 + mrow) * 64 + quad * 8 + step * 32);
#pragma unroll
    for (int j = 0; j < 4; ++j)
      bfv[j] = *(const short8*)(Bs + (j * 16 + mrow) * 64 + quad * 8 + step * 32);
#pragma unroll
    for (int i = 0; i < 4; ++i) {
#pragma unroll
      for (int j = 0; j < 4; ++j)
        acc[i][j] = __builtin_amdgcn_mfma_f32_16x16x32_bf16(af[i], bfv[j], acc[i][j], 0, 0, 0);
      accd[i] = __builtin_amdgcn_mfma_f32_16x16x32_bf16(af[i], ksf[step], accd[i], 0, 0, 0);
    }
  }

#pragma unroll
  for (int i = 0; i < 4; ++i) {
    float inv[4];
#pragma unroll
    for (int r = 0; r < 4; ++r) {
      float den = __shfl(accd[i][r], lane & 48);   // broadcast col-0 lane of quad group
      inv[r] = 1.0f / (den + EPS_ATTN_C);
    }
#pragma unroll
    for (int j = 0; j < 4; ++j) {
      int d = j * 16 + mrow;
#pragma unroll
      for (int r = 0; r < 4; ++r) {
        int s = s0 + wave * 64 + i * 16 + quad * 4 + r;
        attn[((size_t)(b * Sc + s)) * (Hc * DHc) + h * DHc + d] = f2b(acc[i][j][r] * inv[r]);
      }
    }
  }
}

extern "C" void kernel_launch(void* const* d_in, const int* in_sizes, int n_in,
                              void* d_out, int out_size, void* d_ws, size_t ws_size,
                              hipStream_t stream) {
  const float* x     = (const float*)d_in[0];
  const float* ln1_g = (const float*)d_in[1];
  const float* ln1_b = (const float*)d_in[2];
  const float* wq    = (const float*)d_in[3];
  const float* wk    = (const float*)d_in[4];
  const float* wv    = (const float*)d_in[5];
  const float* proj  = (const float*)d_in[6];
  const float* wo    = (const float*)d_in[7];
  const float* bo    = (const float*)d_in[8];
  const float* ln2_g = (const float*)d_in[9];
  const float* ln2_b = (const float*)d_in[10];
  const float* w1    = (const float*)d_in[11];
  const float* b1    = (const float*)d_in[12];
  const float* w2    = (const float*)d_in[13];
  const float* b2    = (const float*)d_in[14];
  float* out = (float*)d_out;
  (void)ws_size; (void)in_sizes; (void)n_in; (void)out_size;

  const size_t TOK = (size_t)Bc * Sc;           // 16384
  const size_t REG = TOK * Dc * sizeof(bf16);   // 32 MB
  char* ws = (char*)d_ws;
  bf16* R0 = (bf16*)(ws + 0 * REG);             // h -> qf -> h2
  bf16* R1 = (bf16*)(ws + 1 * REG);             // q -> kf -> mid(lo)
  bf16* R2 = (bf16*)(ws + 2 * REG);             // k -> [kv partials] -> attn -> mid(hi)
  bf16* R3 = (bf16*)(ws + 3 * REG);             // v
  bf16* mid = R1;                               // TOK x 2048 bf16 spans R1+R2
  float* kvpart = (float*)R2;                                   // 16 MB (aliases R2)
  float* kspart = (float*)((char*)R2 + (size_t)64 * KVSPLIT * 4096 * 4);  // 256 KB
  char* p = ws + 4 * REG;
  bf16* kvt   = (bf16*)p;                 p += (size_t)64 * 64 * 64 * 2;         // 512 KB
  bf16* ksb16 = (bf16*)p;                 p += (size_t)64 * 64 * 2;              // 8 KB
  bf16* pjt   = (bf16*)p;                 p += (size_t)64 * 64 * 2;              // 8 KB
  bf16* wqt = (bf16*)p;                   p += (size_t)Dc * Dc * 2;              // 2 MB
  bf16* wkt = (bf16*)p;                   p += (size_t)Dc * Dc * 2;
  bf16* wvt = (bf16*)p;                   p += (size_t)Dc * Dc * 2;
  bf16* wot = (bf16*)p;                   p += (size_t)Dc * Dc * 2;
  bf16* w1t = (bf16*)p;                   p += (size_t)Dc * DFFc * 2;            // 8 MB
  bf16* w2t = (bf16*)p;                   p += (size_t)Dc * DFFc * 2;            // 8 MB

  dim3 blk(256);
  // 0. transpose+convert weights (and proj) to bf16 B^T form
  tcvt_kernel<<<dim3(Dc / 32, Dc / 32), blk, 0, stream>>>(wq, wqt, Dc, Dc);
  tcvt_kernel<<<dim3(Dc / 32, Dc / 32), blk, 0, stream>>>(wk, wkt, Dc, Dc);
  tcvt_kernel<<<dim3(Dc / 32, Dc / 32), blk, 0, stream>>>(wv, wvt, Dc, Dc);
  tcvt_kernel<<<dim3(Dc / 32, Dc / 32), blk, 0, stream>>>(wo, wot, Dc, Dc);
  tcvt_kernel<<<dim3(DFFc / 32, Dc / 32), blk, 0, stream>>>(w1, w1t, Dc, DFFc);
  tcvt_kernel<<<dim3(Dc / 32, DFFc / 32), blk, 0, stream>>>(w2, w2t, DFFc, Dc);
  tcvt_kernel<<<dim3(2, 2), blk, 0, stream>>>(proj, pjt, 64, 64);

  // 1. h = LN1(x) -> R0
  ln_kernel<<<dim3(TOK), blk, 0, stream>>>(x, ln1_g, ln1_b, R0);

  // 2-4. q,k,v = h @ {wq,wk,wv}
  dim3 gD(Dc / 128, TOK / 128);
  mgemm_kernel<0><<<gD, blk, 0, stream>>>((const ushort*)R0, (const ushort*)wqt, nullptr, nullptr,
                                          nullptr, R1, TOK, Dc, Dc, Dc, Dc);
  mgemm_kernel<0><<<gD, blk, 0, stream>>>((const ushort*)R0, (const ushort*)wkt, nullptr, nullptr,
                                          nullptr, R2, TOK, Dc, Dc, Dc, Dc);
  mgemm_kernel<0><<<gD, blk, 0, stream>>>((const ushort*)R0, (const ushort*)wvt, nullptr, nullptr,
                                          nullptr, R3, TOK, Dc, Dc, Dc, Dc);

  // 5-6. qf = fm(q): R1 -> R0 ; kf = fm(k): R2 -> R1
  dim3 gF(Sc / 256, Hc, Bc);
  fm_mfma<<<gF, blk, 0, stream>>>((const ushort*)R1, (const ushort*)pjt, R0);
  fm_mfma<<<gF, blk, 0, stream>>>((const ushort*)R2, (const ushort*)pjt, R1);

  // 7. kv partials (split-K over S, MFMA) + reduce to bf16 kv^T / ksum
  kvp_mfma<<<dim3(KVSPLIT, Bc * Hc), blk, 0, stream>>>((const ushort*)R1, (const ushort*)R3,
                                                       kvpart, kspart);
  kvr_kernel<<<dim3(Bc * Hc), blk, 0, stream>>>(kvpart, kspart, kvt, ksb16);

  // 8. attn: qf(R0) x kvt -> R2
  attn_mfma<<<gF, blk, 0, stream>>>((const ushort*)R0, (const ushort*)kvt,
                                    (const ushort*)ksb16, R2);

  // 9. x2 = x + attn @ wo + bo -> d_out (f32)
  mgemm_kernel<1><<<gD, blk, 0, stream>>>((const ushort*)R2, (const ushort*)wot, bo, x,
                                          out, nullptr, TOK, Dc, Dc, Dc, Dc);

  // 10. h2 = LN2(x2) -> R0
  ln_kernel<<<dim3(TOK), blk, 0, stream>>>(out, ln2_g, ln2_b, R0);

  // 11-12. FFN in two DFF halves (mid aliases R1+R2)
  dim3 gW1(2048 / 128, TOK / 128);
  mgemm_kernel<2><<<gW1, blk, 0, stream>>>((const ushort*)R0, (const ushort*)w1t, b1, nullptr,
                                           nullptr, mid, TOK, 2048, Dc, Dc, Dc);
  mgemm_kernel<3><<<gD, blk, 0, stream>>>((const ushort*)mid, (const ushort*)w2t, b2, out,
                                          out, nullptr, TOK, Dc, 2048, 2048, DFFc);
  mgemm_kernel<2><<<gW1, blk, 0, stream>>>((const ushort*)R0, (const ushort*)(w1t + (size_t)2048 * Dc), b1 + 2048,
                                           nullptr, nullptr, mid, TOK, 2048, Dc, Dc, Dc);
  mgemm_kernel<3><<<gD, blk, 0, stream>>>((const ushort*)mid, (const ushort*)(w2t + 2048), nullptr, out,
                                          out, nullptr, TOK, Dc, 2048, 2048, DFFc);
}

// Round 6
// 832.079 us; speedup vs baseline: 11.0960x; 1.0846x over previous
//
#include <hip/hip_runtime.h>
#include <hip/hip_bf16.h>
#include <math.h>

using bf16 = __hip_bfloat16;
typedef __attribute__((ext_vector_type(8))) short short8;
typedef __attribute__((ext_vector_type(4))) float f32x4;

constexpr int Bc = 4, Sc = 4096, Dc = 1024, Hc = 16, DHc = 64, Fc = 64, DFFc = 4096;
constexpr float EPS_LN_C = 1e-5f, EPS_ATTN_C = 1e-6f;
constexpr int KVSPLIT = 16;

static __device__ __forceinline__ float b2f(bf16 v) { return __bfloat162float(v); }
static __device__ __forceinline__ bf16 f2b(float f) { return __float2bfloat16(f); }

// ---------------- block reduction (256 threads, wave64) ----------------
__device__ float block_reduce_sum(float v) {
  __shared__ float red[4];
  int lane = threadIdx.x & 63, wid = threadIdx.x >> 6;
#pragma unroll
  for (int off = 32; off > 0; off >>= 1) v += __shfl_down(v, off, 64);
  __syncthreads();
  if (lane == 0) red[wid] = v;
  __syncthreads();
  return red[0] + red[1] + red[2] + red[3];
}

// ---------------- LayerNorm: one block per row (D=1024) ----------------
__global__ void ln_kernel(const float* __restrict__ x, const float* __restrict__ g,
                          const float* __restrict__ bta, bf16* __restrict__ out) {
  int row = blockIdx.x;
  const float* xr = x + (size_t)row * Dc;
  int t = threadIdx.x;
  float v[4];
#pragma unroll
  for (int i = 0; i < 4; ++i) v[i] = xr[t + 256 * i];
  float s = block_reduce_sum(v[0] + v[1] + v[2] + v[3]);
  float mu = s * (1.f / Dc);
  float vs = 0.f;
#pragma unroll
  for (int i = 0; i < 4; ++i) { float d = v[i] - mu; vs += d * d; }
  vs = block_reduce_sum(vs);
  float rstd = rsqrtf(vs * (1.f / Dc) + EPS_LN_C);
  bf16* orow = out + (size_t)row * Dc;
#pragma unroll
  for (int i = 0; i < 4; ++i) {
    int c = t + 256 * i;
    orow[c] = f2b((v[i] - mu) * rstd * g[c] + bta[c]);
  }
}

// ------------- transpose + convert: in f32 [K,N] -> out bf16 [N,K] -------------
__global__ void tcvt_kernel(const float* __restrict__ in, bf16* __restrict__ out,
                            int K, int N) {
  __shared__ float t[32][33];
  int n0 = blockIdx.x * 32, k0 = blockIdx.y * 32;
  int tid = threadIdx.x;
#pragma unroll
  for (int i = 0; i < 4; ++i) {
    int idx = tid + 256 * i;
    int r = idx >> 5, c = idx & 31;
    t[r][c] = in[(size_t)(k0 + r) * N + n0 + c];
  }
  __syncthreads();
#pragma unroll
  for (int i = 0; i < 4; ++i) {
    int idx = tid + 256 * i;
    int r = idx >> 5, c = idx & 31;
    out[(size_t)(n0 + r) * K + k0 + c] = f2b(t[c][r]);
  }
}

// ---------------- MFMA GEMM: C[M,N] = A(bf16)[M,lda] * Bt(bf16)[N,ldbt]^T ----------------
// 128x128 tile, BK=32, 4 waves each 64x64 (4x4 mfma_f32_16x16x32_bf16).
// XCD-aware swizzle: xcd = bid%8 owns contiguous M-supertile, iterates N fastest
// (A-supertile ~4MB streams in its own L2; B stays L2-resident).
// EPI: 0 bf16 store | 1 f32 +bias+res | 2 bf16 gelu(+bias) | 3 f32 +(bias?)+res
//      4 QKV split: col c -> outB + (c>>10)*TOK*1024, col c&1023
template <int EPI>
__global__ __launch_bounds__(256, 2)
void mgemm_kernel(const ushort* __restrict__ A, const ushort* __restrict__ Bt,
                  const float* __restrict__ bias, const float* __restrict__ res,
                  float* __restrict__ outF, bf16* __restrict__ outB,
                  int M, int N, int K, int lda, int ldbt) {
  __shared__ ushort As[128 * 32];
  __shared__ ushort Bs[128 * 32];
  int tid = threadIdx.x;
  int wave = tid >> 6, lane = tid & 63;

  int nn = gridDim.x, nm = gridDim.y;
  int bid = blockIdx.y * nn + blockIdx.x;
  int mtile, ntile;
  if ((nm & 7) == 0) {          // XCD swizzle (bijection; perf-only heuristic)
    int xcd = bid & 7, s = bid >> 3;
    int mpx = nm >> 3;
    int mloc = s / nn;
    ntile = s - mloc * nn;
    mtile = xcd * mpx + mloc;
  } else {
    mtile = blockIdx.y; ntile = blockIdx.x;
  }
  int row0 = mtile * 128, col0 = ntile * 128;
  int wm = (wave >> 1) * 64, wn = (wave & 1) * 64;
  int mrow = lane & 15, quad = lane >> 4;

  f32x4 acc[4][4] = {};

  int c0 = tid, c1 = tid + 256;
  const ushort* aP0 = A + (size_t)(row0 + (c0 >> 2)) * lda + (c0 & 3) * 8;
  const ushort* aP1 = A + (size_t)(row0 + (c1 >> 2)) * lda + (c1 & 3) * 8;
  const ushort* bP0 = Bt + (size_t)(col0 + (c0 >> 2)) * ldbt + (c0 & 3) * 8;
  const ushort* bP1 = Bt + (size_t)(col0 + (c1 >> 2)) * ldbt + (c1 & 3) * 8;
  ushort* aL0 = As + c0 * 8;
  ushort* aL1 = As + c1 * 8;
  ushort* bL0 = Bs + c0 * 8;
  ushort* bL1 = Bs + c1 * 8;

  for (int k0 = 0; k0 < K; k0 += 32) {
    __syncthreads();
    __builtin_amdgcn_global_load_lds((const __attribute__((address_space(1))) void*)aP0,
                                     (__attribute__((address_space(3))) void*)aL0, 16, 0, 0);
    __builtin_amdgcn_global_load_lds((const __attribute__((address_space(1))) void*)aP1,
                                     (__attribute__((address_space(3))) void*)aL1, 16, 0, 0);
    __builtin_amdgcn_global_load_lds((const __attribute__((address_space(1))) void*)bP0,
                                     (__attribute__((address_space(3))) void*)bL0, 16, 0, 0);
    __builtin_amdgcn_global_load_lds((const __attribute__((address_space(1))) void*)bP1,
                                     (__attribute__((address_space(3))) void*)bL1, 16, 0, 0);
    aP0 += 32; aP1 += 32; bP0 += 32; bP1 += 32;
    __syncthreads();

    short8 af[4], bfv[4];
#pragma unroll
    for (int i = 0; i < 4; ++i)
      af[i] = *(const short8*)(As + (wm + i * 16 + mrow) * 32 + quad * 8);
#pragma unroll
    for (int j = 0; j < 4; ++j)
      bfv[j] = *(const short8*)(Bs + (wn + j * 16 + mrow) * 32 + quad * 8);
#pragma unroll
    for (int i = 0; i < 4; ++i)
#pragma unroll
      for (int j = 0; j < 4; ++j)
        acc[i][j] = __builtin_amdgcn_mfma_f32_16x16x32_bf16(af[i], bfv[j], acc[i][j], 0, 0, 0);
  }

#pragma unroll
  for (int i = 0; i < 4; ++i) {
#pragma unroll
    for (int j = 0; j < 4; ++j) {
      int rb = row0 + wm + i * 16 + quad * 4;
      int c = col0 + wn + j * 16 + mrow;
#pragma unroll
      for (int r = 0; r < 4; ++r) {
        int rr = rb + r;
        float v = acc[i][j][r];
        if (EPI == 1 || EPI == 2) v += bias[c];
        if (EPI == 3) { if (bias) v += bias[c]; }
        if (EPI == 2) v = 0.5f * v * (1.f + erff(v * 0.70710678118654752f));
        if (EPI == 1 || EPI == 3) v += res[(size_t)rr * N + c];
        if (EPI == 4) {
          // QKV split store: buffers of TOK x 1024 laid contiguously
          outB[((size_t)(c >> 10) * (size_t)(Bc * Sc) + rr) * 1024 + (c & 1023)] = f2b(v);
        } else if (EPI == 0 || EPI == 2) {
          outB[(size_t)rr * N + c] = f2b(v);
        } else {
          outF[(size_t)rr * N + c] = v;
        }
      }
    }
  }
}

// ======== fm_mfma: per-head [256s x 64] @ projT[64f][64d]^T, relu+eps ========
__global__ __launch_bounds__(256, 2)
void fm_mfma(const ushort* __restrict__ qin, const ushort* __restrict__ pjt,
             bf16* __restrict__ qf) {
  __shared__ ushort As[256 * 64];   // [s_local][d]
  __shared__ ushort Bs[64 * 64];    // [f][d]
  int t = threadIdx.x;
  int wave = t >> 6, lane = t & 63;
  int mrow = lane & 15, quad = lane >> 4;
  int b = blockIdx.z, h = blockIdx.y, s0 = blockIdx.x * 256;
  const ushort* abase = qin + ((size_t)b * Sc + s0) * (Hc * DHc) + h * DHc;

#pragma unroll
  for (int i = 0; i < 8; ++i) {
    int c = t + 256 * i;
    int row = c >> 3, col = (c & 7) * 8;
    __builtin_amdgcn_global_load_lds(
        (const __attribute__((address_space(1))) void*)(abase + (size_t)row * (Hc * DHc) + col),
        (__attribute__((address_space(3))) void*)(As + c * 8), 16, 0, 0);
  }
#pragma unroll
  for (int i = 0; i < 2; ++i) {
    int c = t + 256 * i;
    __builtin_amdgcn_global_load_lds(
        (const __attribute__((address_space(1))) void*)(pjt + c * 8),
        (__attribute__((address_space(3))) void*)(Bs + c * 8), 16, 0, 0);
  }
  __syncthreads();

  f32x4 acc[4][4] = {};
#pragma unroll
  for (int step = 0; step < 2; ++step) {
    short8 af[4], bfv[4];
#pragma unroll
    for (int i = 0; i < 4; ++i)
      af[i] = *(const short8*)(As + (wave * 64 + i * 16 + mrow) * 64 + quad * 8 + step * 32);
#pragma unroll
    for (int j = 0; j < 4; ++j)
      bfv[j] = *(const short8*)(Bs + (j * 16 + mrow) * 64 + quad * 8 + step * 32);
#pragma unroll
    for (int i = 0; i < 4; ++i)
#pragma unroll
      for (int j = 0; j < 4; ++j)
        acc[i][j] = __builtin_amdgcn_mfma_f32_16x16x32_bf16(af[i], bfv[j], acc[i][j], 0, 0, 0);
  }

  size_t obase = ((size_t)(b * Hc + h)) * Sc + s0;
#pragma unroll
  for (int i = 0; i < 4; ++i) {
#pragma unroll
    for (int j = 0; j < 4; ++j) {
      int f = j * 16 + mrow;
#pragma unroll
      for (int r = 0; r < 4; ++r) {
        int s = wave * 64 + i * 16 + quad * 4 + r;
        float v = fmaxf(acc[i][j][r], 0.f) + EPS_ATTN_C;
        qf[(obase + s) * Fc + f] = f2b(v);
      }
    }
  }
}

// ======== kvp_mfma: split-K kf^T v (+ ksum) via LDS transpose ========
__global__ __launch_bounds__(256, 2)
void kvp_mfma(const ushort* __restrict__ kf, const ushort* __restrict__ v,
              float* __restrict__ kvp, float* __restrict__ ksump) {
  constexpr int LT = 72;
  __shared__ ushort kfT[64 * LT];   // [f][s]
  __shared__ ushort vT[64 * LT];    // [d][s]
  int t = threadIdx.x;
  int wave = t >> 6, lane = t & 63;
  int mrow = lane & 15, quad = lane >> 4;
  int split = blockIdx.x, bh = blockIdx.y;
  int b = bh >> 4, h = bh & 15;
  int sbase = split * (Sc / KVSPLIT);

  short8 ones, zero;
#pragma unroll
  for (int i = 0; i < 8; ++i) { ones[i] = (short)0x3F80; zero[i] = 0; }
  short8 bks = (mrow == 0) ? ones : zero;

  f32x4 acc[4] = {};
  f32x4 accks = {};

  for (int sc = 0; sc < Sc / KVSPLIT; sc += 64) {
    __syncthreads();
    int sl = t >> 2, c8 = (t & 3) * 8;
    const ushort* kp = kf + (((size_t)bh * Sc) + sbase + sc + sl) * Fc + c8;
    const ushort* vp = v + (((size_t)b * Sc) + sbase + sc + sl) * (Hc * DHc) + h * DHc + c8;
#pragma unroll
    for (int half = 0; half < 2; ++half) {
      short8 kv8 = *(const short8*)(kp + half * 32);
      short8 vv8 = *(const short8*)(vp + half * 32);
#pragma unroll
      for (int jj = 0; jj < 8; ++jj) {
        kfT[(c8 + half * 32 + jj) * LT + sl] = (ushort)kv8[jj];
        vT[(c8 + half * 32 + jj) * LT + sl] = (ushort)vv8[jj];
      }
    }
    __syncthreads();
#pragma unroll
    for (int step = 0; step < 2; ++step) {
      short8 af = *(const short8*)(kfT + (wave * 16 + mrow) * LT + quad * 8 + step * 32);
      short8 bfv[4];
#pragma unroll
      for (int j = 0; j < 4; ++j)
        bfv[j] = *(const short8*)(vT + (j * 16 + mrow) * LT + quad * 8 + step * 32);
#pragma unroll
      for (int j = 0; j < 4; ++j)
        acc[j] = __builtin_amdgcn_mfma_f32_16x16x32_bf16(af, bfv[j], acc[j], 0, 0, 0);
      accks = __builtin_amdgcn_mfma_f32_16x16x32_bf16(af, bks, accks, 0, 0, 0);
    }
  }

  size_t pbase = (size_t)bh * KVSPLIT + split;
#pragma unroll
  for (int j = 0; j < 4; ++j) {
    int d = j * 16 + mrow;
#pragma unroll
    for (int r = 0; r < 4; ++r) {
      int f = wave * 16 + quad * 4 + r;
      kvp[(pbase * 64 + f) * 64 + d] = acc[j][r];
    }
  }
  if (mrow == 0) {
#pragma unroll
    for (int r = 0; r < 4; ++r) {
      int f = wave * 16 + quad * 4 + r;
      ksump[pbase * 64 + f] = accks[r];
    }
  }
}

// ------- kv reduce: sums KVSPLIT partials -> kvt bf16 [d][f], ksum bf16 -------
__global__ void kvr_kernel(const float* __restrict__ kvp, const float* __restrict__ ksump,
                           bf16* __restrict__ kvt, bf16* __restrict__ ksum16) {
  int bh = blockIdx.x;
  int t = threadIdx.x;
#pragma unroll
  for (int i = 0; i < 16; ++i) {
    int idx = t + 256 * i;
    int f = idx >> 6, d = idx & 63;
    float s = 0.f;
#pragma unroll
    for (int j = 0; j < KVSPLIT; ++j)
      s += kvp[((size_t)bh * KVSPLIT + j) * 4096 + idx];
    kvt[((size_t)bh * 64 + d) * 64 + f] = f2b(s);
  }
  if (t < 64) {
    float s = 0.f;
#pragma unroll
    for (int j = 0; j < KVSPLIT; ++j)
      s += ksump[((size_t)bh * KVSPLIT + j) * 64 + t];
    ksum16[bh * 64 + t] = f2b(s);
  }
}

// ======== attn_mfma: per-head (qf @ kv) / (qf.ksum + eps) ========
__global__ __launch_bounds__(256, 2)
void attn_mfma(const ushort* __restrict__ qf, const ushort* __restrict__ kvt,
               const ushort* __restrict__ ksum16, bf16* __restrict__ attn) {
  __shared__ ushort As[256 * 64];   // [s_local][f]
  __shared__ ushort Bs[64 * 64];    // [d][f]
  int t = threadIdx.x;
  int wave = t >> 6, lane = t & 63;
  int mrow = lane & 15, quad = lane >> 4;
  int b = blockIdx.z, h = blockIdx.y, s0 = blockIdx.x * 256;
  int bh = b * Hc + h;
  const ushort* abase = qf + (((size_t)bh * Sc) + s0) * Fc;
  const ushort* bbase = kvt + (size_t)bh * 4096;

#pragma unroll
  for (int i = 0; i < 8; ++i) {
    int c = t + 256 * i;
    __builtin_amdgcn_global_load_lds(
        (const __attribute__((address_space(1))) void*)(abase + c * 8),
        (__attribute__((address_space(3))) void*)(As + c * 8), 16, 0, 0);
  }
#pragma unroll
  for (int i = 0; i < 2; ++i) {
    int c = t + 256 * i;
    __builtin_amdgcn_global_load_lds(
        (const __attribute__((address_space(1))) void*)(bbase + c * 8),
        (__attribute__((address_space(3))) void*)(Bs + c * 8), 16, 0, 0);
  }
  short8 zero;
#pragma unroll
  for (int i = 0; i < 8; ++i) zero[i] = 0;
  short8 ksf[2];
#pragma unroll
  for (int step = 0; step < 2; ++step) {
    short8 kv8 = *(const short8*)(ksum16 + bh * 64 + quad * 8 + step * 32);
    ksf[step] = (mrow == 0) ? kv8 : zero;
  }
  __syncthreads();

  f32x4 acc[4][4] = {};
  f32x4 accd[4] = {};
#pragma unroll
  for (int step = 0; step < 2; ++step) {
    short8 af[4], bfv[4];
#pragma unroll
    for (int i = 0; i < 4; ++i)
      af[i] = *(const short8*)(As + (wave * 64 + i * 16 + mrow) * 64 + quad * 8 + step * 32);
#pragma unroll
    for (int j = 0; j < 4; ++j)
      bfv[j] = *(const short8*)(Bs + (j * 16 + mrow) * 64 + quad * 8 + step * 32);
#pragma unroll
    for (int i = 0; i < 4; ++i) {
#pragma unroll
      for (int j = 0; j < 4; ++j)
        acc[i][j] = __builtin_amdgcn_mfma_f32_16x16x32_bf16(af[i], bfv[j], acc[i][j], 0, 0, 0);
      accd[i] = __builtin_amdgcn_mfma_f32_16x16x32_bf16(af[i], ksf[step], accd[i], 0, 0, 0);
    }
  }

#pragma unroll
  for (int i = 0; i < 4; ++i) {
    float inv[4];
#pragma unroll
    for (int r = 0; r < 4; ++r) {
      float den = __shfl(accd[i][r], lane & 48);
      inv[r] = 1.0f / (den + EPS_ATTN_C);
    }
#pragma unroll
    for (int j = 0; j < 4; ++j) {
      int d = j * 16 + mrow;
#pragma unroll
      for (int r = 0; r < 4; ++r) {
        int s = s0 + wave * 64 + i * 16 + quad * 4 + r;
        attn[((size_t)(b * Sc + s)) * (Hc * DHc) + h * DHc + d] = f2b(acc[i][j][r] * inv[r]);
      }
    }
  }
}

extern "C" void kernel_launch(void* const* d_in, const int* in_sizes, int n_in,
                              void* d_out, int out_size, void* d_ws, size_t ws_size,
                              hipStream_t stream) {
  const float* x     = (const float*)d_in[0];
  const float* ln1_g = (const float*)d_in[1];
  const float* ln1_b = (const float*)d_in[2];
  const float* wq    = (const float*)d_in[3];
  const float* wk    = (const float*)d_in[4];
  const float* wv    = (const float*)d_in[5];
  const float* proj  = (const float*)d_in[6];
  const float* wo    = (const float*)d_in[7];
  const float* bo    = (const float*)d_in[8];
  const float* ln2_g = (const float*)d_in[9];
  const float* ln2_b = (const float*)d_in[10];
  const float* w1    = (const float*)d_in[11];
  const float* b1    = (const float*)d_in[12];
  const float* w2    = (const float*)d_in[13];
  const float* b2    = (const float*)d_in[14];
  float* out = (float*)d_out;
  (void)ws_size; (void)in_sizes; (void)n_in; (void)out_size;

  const size_t TOK = (size_t)Bc * Sc;           // 16384
  const size_t REG = TOK * Dc * sizeof(bf16);   // 32 MB
  char* ws = (char*)d_ws;
  bf16* R0 = (bf16*)(ws + 0 * REG);             // h -> qf -> h2
  bf16* R1 = (bf16*)(ws + 1 * REG);             // q -> kf -> mid(lo)
  bf16* R2 = (bf16*)(ws + 2 * REG);             // k -> [kv partials] -> attn -> mid(hi)
  bf16* R3 = (bf16*)(ws + 3 * REG);             // v
  bf16* mid = R1;
  float* kvpart = (float*)R2;                                   // 16 MB (aliases R2)
  float* kspart = (float*)((char*)R2 + (size_t)64 * KVSPLIT * 4096 * 4);
  char* p = ws + 4 * REG;
  bf16* kvt   = (bf16*)p;                 p += (size_t)64 * 64 * 64 * 2;
  bf16* ksb16 = (bf16*)p;                 p += (size_t)64 * 64 * 2;
  bf16* pjt   = (bf16*)p;                 p += (size_t)64 * 64 * 2;
  bf16* wqt = (bf16*)p;                   p += (size_t)Dc * Dc * 2;   // wqt/wkt/wvt contiguous:
  bf16* wkt = (bf16*)p;                   p += (size_t)Dc * Dc * 2;   // single [3072][1024] Bt slab
  bf16* wvt = (bf16*)p;                   p += (size_t)Dc * Dc * 2;
  bf16* wot = (bf16*)p;                   p += (size_t)Dc * Dc * 2;
  bf16* w1t = (bf16*)p;                   p += (size_t)Dc * DFFc * 2;
  bf16* w2t = (bf16*)p;                   p += (size_t)Dc * DFFc * 2;

  dim3 blk(256);
  // 0. transpose+convert weights (and proj) to bf16 B^T form
  tcvt_kernel<<<dim3(Dc / 32, Dc / 32), blk, 0, stream>>>(wq, wqt, Dc, Dc);
  tcvt_kernel<<<dim3(Dc / 32, Dc / 32), blk, 0, stream>>>(wk, wkt, Dc, Dc);
  tcvt_kernel<<<dim3(Dc / 32, Dc / 32), blk, 0, stream>>>(wv, wvt, Dc, Dc);
  tcvt_kernel<<<dim3(Dc / 32, Dc / 32), blk, 0, stream>>>(wo, wot, Dc, Dc);
  tcvt_kernel<<<dim3(DFFc / 32, Dc / 32), blk, 0, stream>>>(w1, w1t, Dc, DFFc);
  tcvt_kernel<<<dim3(Dc / 32, DFFc / 32), blk, 0, stream>>>(w2, w2t, DFFc, Dc);
  tcvt_kernel<<<dim3(2, 2), blk, 0, stream>>>(proj, pjt, 64, 64);

  // 1. h = LN1(x) -> R0
  ln_kernel<<<dim3(TOK), blk, 0, stream>>>(x, ln1_g, ln1_b, R0);

  // 2. fused QKV: [TOK,1024] @ [3072,1024]^T -> split into R1,R2,R3 (EPI=4)
  dim3 gQKV(3072 / 128, TOK / 128);
  mgemm_kernel<4><<<gQKV, blk, 0, stream>>>((const ushort*)R0, (const ushort*)wqt, nullptr, nullptr,
                                            nullptr, R1, TOK, 3072, Dc, Dc, Dc);

  // 5-6. qf = fm(q): R1 -> R0 ; kf = fm(k): R2 -> R1
  dim3 gF(Sc / 256, Hc, Bc);
  fm_mfma<<<gF, blk, 0, stream>>>((const ushort*)R1, (const ushort*)pjt, R0);
  fm_mfma<<<gF, blk, 0, stream>>>((const ushort*)R2, (const ushort*)pjt, R1);

  // 7. kv partials + reduce
  kvp_mfma<<<dim3(KVSPLIT, Bc * Hc), blk, 0, stream>>>((const ushort*)R1, (const ushort*)R3,
                                                       kvpart, kspart);
  kvr_kernel<<<dim3(Bc * Hc), blk, 0, stream>>>(kvpart, kspart, kvt, ksb16);

  // 8. attn: qf(R0) x kvt -> R2
  attn_mfma<<<gF, blk, 0, stream>>>((const ushort*)R0, (const ushort*)kvt,
                                    (const ushort*)ksb16, R2);

  // 9. x2 = x + attn @ wo + bo -> d_out (f32)
  dim3 gD(Dc / 128, TOK / 128);
  mgemm_kernel<1><<<gD, blk, 0, stream>>>((const ushort*)R2, (const ushort*)wot, bo, x,
                                          out, nullptr, TOK, Dc, Dc, Dc, Dc);

  // 10. h2 = LN2(x2) -> R0
  ln_kernel<<<dim3(TOK), blk, 0, stream>>>(out, ln2_g, ln2_b, R0);

  // 11-12. FFN in two DFF halves (mid aliases R1+R2)
  dim3 gW1(2048 / 128, TOK / 128);
  mgemm_kernel<2><<<gW1, blk, 0, stream>>>((const ushort*)R0, (const ushort*)w1t, b1, nullptr,
                                           nullptr, mid, TOK, 2048, Dc, Dc, Dc);
  mgemm_kernel<3><<<gD, blk, 0, stream>>>((const ushort*)mid, (const ushort*)w2t, b2, out,
                                          out, nullptr, TOK, Dc, 2048, 2048, DFFc);
  mgemm_kernel<2><<<gW1, blk, 0, stream>>>((const ushort*)R0, (const ushort*)(w1t + (size_t)2048 * Dc), b1 + 2048,
                                           nullptr, nullptr, mid, TOK, 2048, Dc, Dc, Dc);
  mgemm_kernel<3><<<gD, blk, 0, stream>>>((const ushort*)mid, (const ushort*)(w2t + 2048), nullptr, out,
                                          out, nullptr, TOK, Dc, 2048, 2048, DFFc);
}